// Round 7
// baseline (14173.251 us; speedup 1.0000x reference)
//
#include <hip/hip_runtime.h>
#include <hip/hip_fp16.h>

#define Tn 4096
#define Bn 128
#define Hn 128
#define G3 384
#define NTH 576   // 9 waves: waves 0-7 matvec+gates (MFMA), wave 8 heads+coupling

typedef unsigned short u16;
typedef unsigned int u32;
typedef _Float16 f16;
typedef _Float16 f16x8 __attribute__((ext_vector_type(8)));
typedef float f32x4 __attribute__((ext_vector_type(4)));

__device__ __forceinline__ float sigm(float v) { return 1.f / (1.f + __expf(-v)); }
__device__ __forceinline__ float tanh_fast(float v) {
  v = fminf(fmaxf(v, -15.f), 15.f);
  float e = __expf(-2.f * v);
  return (1.f - e) / (1.f + e);
}
__device__ __forceinline__ u16 f2h(float f) { return __half_as_ushort(__float2half(f)); }
__device__ __forceinline__ float h2f(u16 u) { return __half2float(__ushort_as_half(u)); }
// X tile byte offset: row-major [16][128] f16, 16B chunks XOR-swizzled by row
// (lanes 0-15 of an A-read hit distinct banks -> conflict-free ds_read_b128).
__device__ __forceinline__ int xsw(int row, int col) {
  return row * 256 + ((((col >> 3) ^ (row & 7))) << 4) + ((col & 7) << 1);
}
#define MFMA16(a, b, c) __builtin_amdgcn_mfma_f32_16x16x32_f16((a), (b), (c), 0, 0, 0)

// ============ combo: blocks 0-7 = encoder (16 rows each), 8-15 = decoder ============
__global__ __launch_bounds__(NTH, 1) void combo_kernel(
    const float* __restrict__ x, const float* __restrict__ Wi_e,
    const float* __restrict__ Wh_e, const float* __restrict__ bi_e,
    const float* __restrict__ bhn_e, u16* __restrict__ hx,
    float* __restrict__ enc_h,
    const float* __restrict__ eps, const float* __restrict__ Wi_d,
    const float* __restrict__ Wh_d, const float* __restrict__ bhn_d,
    const float* __restrict__ W_shift, const float* __restrict__ b_shift,
    const float* __restrict__ W_lsc, const float* __restrict__ b_lsc,
    const float* __restrict__ W_pi, const float* __restrict__ b_pi,
    const float* __restrict__ W_mu, const float* __restrict__ b_mu,
    const float* __restrict__ W_ls, const float* __restrict__ b_ls,
    const u16* __restrict__ gi, float* __restrict__ out,
    float* __restrict__ dec_h, float* __restrict__ dec_pred,
    int enc_t0, int dec_t0, int Tc)
{
  const int tid = threadIdx.x;
  const int w = tid >> 6, l = tid & 63;
  const int lj = l & 15, lg = l >> 4;
  __shared__ __align__(16) f16 Xl[16 * 128];       // fp16 h, swizzled
  __shared__ __align__(16) float heads_l[32 * 20]; // [n][row(pad 20)]
  __shared__ float pred_s[16];
  __shared__ float xt_s[16];

  const int bid = blockIdx.x;
  const bool is_enc = bid < 8;
  const int bq = is_enc ? bid : bid - 8;
  const int b0 = bq * 16;
  if (is_enc) { if (enc_t0 < 0) return; } else { if (dec_t0 < 0) return; }
  const int t0 = is_enc ? enc_t0 : dec_t0;
  const float* Wh = is_enc ? Wh_e : Wh_d;

  // ---- per-role persistent register state ----
  int col = 0, r0 = lg * 4;
  f16x8 Br[4], Bz[4], Bnn[4];          // matvec B-frags (weights, resident)
  float wr0 = 0, wz0 = 0, wn0 = 0, bhn = 0;
  float wier = 0, wiez = 0, wien = 0, bier = 0, biez = 0, bien = 0;
  float hprev[4] = {0, 0, 0, 0};
  f16x8 Hb0[4], Hb1[4];                // heads B-frags (wave 8, dec)
  float hb0 = 0, hb1 = 0;
  float e_cur = 0, xv = 0;
  const int crow = l >> 2, ckq = l & 3;

  if (w < 8) {
    col = w * 16 + lj;                 // j in 0..127; tiles {j, 128+j, 256+j}
#pragma unroll
    for (int kk = 0; kk < 4; ++kk) {
      f16x8 r_, z_, n_;
#pragma unroll
      for (int jj = 0; jj < 8; ++jj) {
        int k = kk * 32 + lg * 8 + jj;
        r_[jj] = (f16)Wh[k * G3 + col];
        z_[jj] = (f16)Wh[k * G3 + 128 + col];
        n_[jj] = (f16)Wh[k * G3 + 256 + col];
      }
      Br[kk] = r_; Bz[kk] = z_; Bnn[kk] = n_;
    }
    if (is_enc) {
      wier = Wi_e[col]; wiez = Wi_e[128 + col]; wien = Wi_e[256 + col];
      bier = bi_e[col]; biez = bi_e[128 + col]; bien = bi_e[256 + col];
      bhn = bhn_e[col];
    } else {
      wr0 = Wi_d[col]; wz0 = Wi_d[128 + col]; wn0 = Wi_d[256 + col];
      bhn = bhn_d[col];
    }
#pragma unroll
    for (int q = 0; q < 4; ++q) {
      int row = r0 + q;
      float hv = 0.f;
      if (t0) hv = (is_enc ? enc_h : dec_h)[(size_t)(b0 + row) * Hn + col];
      hprev[q] = hv;
      *(f16*)((char*)Xl + xsw(row, col)) = (f16)hv;
    }
  } else if (!is_enc) {
    // heads weights: n0=lj, n1=16+lj (n>=17 zero)
#pragma unroll
    for (int kk = 0; kk < 4; ++kk) {
      f16x8 a_, b_;
#pragma unroll
      for (int jj = 0; jj < 8; ++jj) {
        int k = kk * 32 + lg * 8 + jj;
        int n = lj;
        float wv = (n == 0) ? W_shift[k] : (n == 1) ? W_lsc[k]
                 : (n < 7) ? W_pi[k * 5 + n - 2] : (n < 12) ? W_mu[k * 5 + n - 7]
                 : W_ls[k * 5 + n - 12];
        a_[jj] = (f16)wv;
        b_[jj] = (f16)((16 + n) == 16 ? W_ls[k * 5 + 4] : 0.f);
      }
      Hb0[kk] = a_; Hb1[kk] = b_;
    }
    {
      int n = lj;
      hb0 = (n == 0) ? b_shift[0] : (n == 1) ? b_lsc[0] : (n < 7) ? b_pi[n - 2]
           : (n < 12) ? b_mu[n - 7] : b_ls[n - 12];
      hb1 = (n == 0) ? b_ls[4] : 0.f;  // n1=16 only for lj==0
    }
    e_cur = eps[(size_t)(b0 + crow) * Tn + t0];
    if (l < 16) pred_s[l] = t0 ? dec_pred[b0 + l] : 0.f;
  } else {
    if (l < 16) xv = x[(size_t)(b0 + l) * Tn + (Tn - 1 - t0)];
  }
  __syncthreads();

  const u16* gprow = gi + (size_t)bq * Tc * G3 * 16;
  for (int i = 0; i <= Tc; ++i) {
    uint2 g_r = {0, 0}, g_z = {0, 0}, g_n = {0, 0};
    f32x4 ar = {0, 0, 0, 0}, az = {0, 0, 0, 0}, an = {0, 0, 0, 0};
    // ----------------- P1 -----------------
    if (w < 8) {
      if (i < Tc) {
        if (!is_enc) {
          const u16* gp = gprow + (size_t)i * G3 * 16;
          g_r = *(const uint2*)(gp + col * 16 + r0);
          g_z = *(const uint2*)(gp + (128 + col) * 16 + r0);
          g_n = *(const uint2*)(gp + (256 + col) * 16 + r0);
        }
        f16x8 Af[4];
#pragma unroll
        for (int kk = 0; kk < 4; ++kk)
          Af[kk] = *(const f16x8*)((const char*)Xl + lj * 256 +
                                   (((kk * 4 + lg) ^ (lj & 7)) << 4));
#pragma unroll
        for (int kk = 0; kk < 4; ++kk) {
          ar = MFMA16(Af[kk], Br[kk], ar);
          az = MFMA16(Af[kk], Bz[kk], az);
          an = MFMA16(Af[kk], Bnn[kk], an);
        }
      }
    } else if (is_enc) {
      if (l < 16 && i < Tc) {
        xt_s[l] = xv;
        int xi = Tn - 1 - (t0 + i + 1); if (xi < 0) xi = 0;
        xv = x[(size_t)(b0 + l) * Tn + xi];
      }
    } else {
      float e_new = e_cur;
      if (i < Tc) e_new = eps[(size_t)(b0 + crow) * Tn + t0 + i];
      if (i >= 1) {
        f16x8 Af[4];
#pragma unroll
        for (int kk = 0; kk < 4; ++kk)
          Af[kk] = *(const f16x8*)((const char*)Xl + lj * 256 +
                                   (((kk * 4 + lg) ^ (lj & 7)) << 4));
        f32x4 h0 = {0, 0, 0, 0}, h1 = {0, 0, 0, 0};
#pragma unroll
        for (int kk = 0; kk < 4; ++kk) {
          h0 = MFMA16(Af[kk], Hb0[kk], h0);
          h1 = MFMA16(Af[kk], Hb1[kk], h1);
        }
#pragma unroll
        for (int q = 0; q < 4; ++q) { h0[q] += hb0; h1[q] += hb1; }
        *(f32x4*)((char*)heads_l + (size_t)(lj * 80 + lg * 16)) = h0;
        *(f32x4*)((char*)heads_l + (size_t)((16 + lj) * 80 + lg * 16)) = h1;
        // ---- coupling for step s=i-1 (4 lanes/row, k=ckq; lane0 adds k=4) ----
        const float e = e_cur;
        float pi1 = heads_l[(2 + ckq) * 20 + crow];
        float mu1 = heads_l[(7 + ckq) * 20 + crow];
        float ls1 = heads_l[(12 + ckq) * 20 + crow];
        float we1 = __expf(pi1);
        float zz = (e - mu1) * __expf(-ls1);
        float uu = __expf(-fabsf(zz));
        float dd = 1.f / (1.f + uu);
        float c = we1 * ((zz >= 0.f) ? dd : uu * dd);
        float m = we1 * ((zz >= 0.f) ? uu * dd : dd);
        float pp = we1 * uu * dd * dd * __expf(-ls1);
        float S = we1;
        if (ckq == 0) {
          float pi2 = heads_l[6 * 20 + crow];
          float mu2 = heads_l[11 * 20 + crow];
          float ls2 = heads_l[16 * 20 + crow];
          float w2 = __expf(pi2);
          float z2 = (e - mu2) * __expf(-ls2);
          float u2 = __expf(-fabsf(z2));
          float d2 = 1.f / (1.f + u2);
          c += w2 * ((z2 >= 0.f) ? d2 : u2 * d2);
          m += w2 * ((z2 >= 0.f) ? u2 * d2 : d2);
          pp += w2 * u2 * d2 * d2 * __expf(-ls2);
          S += w2;
        }
        c += __shfl_xor(c, 1, 4);  m += __shfl_xor(m, 1, 4);
        pp += __shfl_xor(pp, 1, 4); S += __shfl_xor(S, 1, 4);
        c += __shfl_xor(c, 2, 4);  m += __shfl_xor(m, 2, 4);
        pp += __shfl_xor(pp, 2, 4); S += __shfl_xor(S, 2, 4);
        if (ckq == 0) {
          float shv = heads_l[0 * 20 + crow], lscv = heads_l[1 * 20 + crow];
          float logc = __logf(c), logm = __logf(m);
          float val = logc - logm;
          float ljac = __logf(pp) + __logf(S) - logc - logm;
          float prednew = fmaf(val, __expf(lscv), shv);
          float sp = fmaxf(-e, 0.f) + log1pf(__expf(-fabsf(e)));
          float logp = (-e - 2.f * sp) - lscv - ljac;
          int t = t0 + (i - 1);
          out[(size_t)(b0 + crow) * Tn + t] = logp;
          out[(size_t)Bn * Tn + (size_t)(b0 + crow) * Tn + t] = prednew;
          pred_s[crow] = prednew;
        }
      }
      e_cur = e_new;
    }
    __syncthreads();                                     // B1
    // ----------------- P2: gates (in-register, no gh LDS) -----------------
    if (w < 8 && i < Tc) {
#pragma unroll
      for (int q = 0; q < 4; ++q) {
        int row = r0 + q;
        float gir, giz, gin;
        if (is_enc) {
          float xt = xt_s[row];
          gir = fmaf(xt, wier, bier);
          giz = fmaf(xt, wiez, biez);
          gin = fmaf(xt, wien, bien);
        } else {
          u32 hr = (q < 2) ? (g_r.x >> (q * 16)) : (g_r.y >> ((q - 2) * 16));
          u32 hz = (q < 2) ? (g_z.x >> (q * 16)) : (g_z.y >> ((q - 2) * 16));
          u32 hn = (q < 2) ? (g_n.x >> (q * 16)) : (g_n.y >> ((q - 2) * 16));
          gir = h2f((u16)hr); giz = h2f((u16)hz); gin = h2f((u16)hn);
        }
        float pr = is_enc ? 0.f : pred_s[row];
        float rr = sigm(ar[q] + gir + pr * wr0);
        float zz = sigm(az[q] + giz + pr * wz0);
        float nn = tanh_fast(gin + pr * wn0 + rr * (an[q] + bhn));
        float hn2 = (1.f - zz) * nn + zz * hprev[q];
        hprev[q] = hn2;
        *(f16*)((char*)Xl + xsw(row, col)) = (f16)hn2;
        if (is_enc) hx[((size_t)(b0 + row) * Tc + i) * Hn + col] = f2h(hn2);
      }
    }
    __syncthreads();                                     // B2
  }
  // ---- persist chunk state ----
  if (w < 8) {
#pragma unroll
    for (int q = 0; q < 4; ++q)
      (is_enc ? enc_h : dec_h)[(size_t)(b0 + r0 + q) * Hn + col] = hprev[q];
  } else if (!is_enc && l < 16) {
    dec_pred[b0 + l] = pred_s[l];
  }
}

// ------- GEMM: gi_t[((bq*Tc+tt)*384+col)*16+rb] = hx[m,:] @ Wi_d[1:,:] + bi_d -------
__global__ __launch_bounds__(256) void gemm_gi(
    const u16* __restrict__ A, const float* __restrict__ Wi_d,
    const float* __restrict__ bi_d, u16* __restrict__ C, int Tc)
{
  __shared__ __align__(16) float As[16][64];  // [k][m]
  __shared__ __align__(16) float Ws[16][64];  // [k][n]
  const int tid = threadIdx.x;
  const long m0 = (long)blockIdx.x * 64;
  const int n0 = blockIdx.y * 64;
  const int tx = tid & 15, ty = tid >> 4;
  const int am = tid >> 2, ak = (tid & 3) * 4;
  const int wk = tid >> 4, wn = (tid & 15) * 4;
  float acc[4][4] = {};
  for (int k0 = 0; k0 < Hn; k0 += 16) {
    uint2 a2v = *(const uint2*)(A + (m0 + am) * Hn + k0 + ak);
    float4 w4 = *(const float4*)(Wi_d + (long)(1 + k0 + wk) * G3 + n0 + wn);
    __syncthreads();
    As[ak + 0][am] = h2f((u16)(a2v.x & 0xffffu));
    As[ak + 1][am] = h2f((u16)(a2v.x >> 16));
    As[ak + 2][am] = h2f((u16)(a2v.y & 0xffffu));
    As[ak + 3][am] = h2f((u16)(a2v.y >> 16));
    *(float4*)&Ws[wk][wn] = w4;
    __syncthreads();
#pragma unroll
    for (int kk = 0; kk < 16; ++kk) {
      float4 av = *(const float4*)&As[kk][ty * 4];
      float4 wv = *(const float4*)&Ws[kk][tx * 4];
      float arr[4] = {av.x, av.y, av.z, av.w};
      float wrr[4] = {wv.x, wv.y, wv.z, wv.w};
#pragma unroll
      for (int i = 0; i < 4; ++i)
#pragma unroll
        for (int jj = 0; jj < 4; ++jj) acc[i][jj] = fmaf(arr[i], wrr[jj], acc[i][jj]);
    }
  }
  const float4 bb = *(const float4*)(bi_d + n0 + tx * 4);
  const float br[4] = {bb.x, bb.y, bb.z, bb.w};
  const long b = m0 / Tc;
  const int bq = (int)(b >> 4), rb = (int)(b & 15);
  const int tt0 = (int)(m0 - b * Tc);
#pragma unroll
  for (int i = 0; i < 4; ++i) {
    int tt = tt0 + ty * 4 + i;
    size_t base = ((size_t)(bq * (size_t)Tc + tt)) * G3;
#pragma unroll
    for (int jj = 0; jj < 4; ++jj) {
      int colc = n0 + tx * 4 + jj;
      C[(base + colc) * 16 + rb] = f2h(acc[i][jj] + br[jj]);
    }
  }
}

extern "C" void kernel_launch(void* const* d_in, const int* in_sizes, int n_in,
                              void* d_out, int out_size, void* d_ws, size_t ws_size,
                              hipStream_t stream) {
  const float* x = (const float*)d_in[1];
  const float* eps = (const float*)d_in[2];
  const float* Wi_e = (const float*)d_in[3];
  const float* Wh_e = (const float*)d_in[4];
  const float* bi_e = (const float*)d_in[5];
  const float* bhn_e = (const float*)d_in[6];
  const float* Wi_d = (const float*)d_in[7];
  const float* Wh_d = (const float*)d_in[8];
  const float* bi_d = (const float*)d_in[9];
  const float* bhn_d = (const float*)d_in[10];
  const float* W_shift = (const float*)d_in[11];
  const float* b_shift = (const float*)d_in[12];
  const float* W_lsc = (const float*)d_in[13];
  const float* b_lsc = (const float*)d_in[14];
  const float* W_pi = (const float*)d_in[15];
  const float* b_pi = (const float*)d_in[16];
  const float* W_mu = (const float*)d_in[17];
  const float* b_mu = (const float*)d_in[18];
  const float* W_ls = (const float*)d_in[19];
  const float* b_ls = (const float*)d_in[20];
  float* out = (float*)d_out;

  const size_t stateB = (size_t)(2 * Bn * Hn + Bn) * sizeof(float);
  const size_t stateAl = (stateB + 255) & ~(size_t)255;
  int Tc = 512;
  while (Tc > 64 && stateAl + (size_t)Bn * Tc * (Hn + G3) * 2 > ws_size) Tc >>= 1;
  if (stateAl + (size_t)Bn * Tc * (Hn + G3) * 2 > ws_size) return;

  float* enc_h = (float*)d_ws;
  float* dec_h = enc_h + (size_t)Bn * Hn;
  float* dec_pred = dec_h + (size_t)Bn * Hn;
  u16* hx = (u16*)((char*)d_ws + stateAl);
  u16* gi = hx + (size_t)Bn * Tc * Hn;

  const int Nc = Tn / Tc;
  const dim3 gg((unsigned)(((size_t)Bn * Tc) / 64), G3 / 64);
  for (int k = 0; k <= Nc; ++k) {
    int enc_t0 = (k < Nc) ? k * Tc : -1;
    int dec_t0 = (k >= 1) ? (k - 1) * Tc : -1;
    combo_kernel<<<16, NTH, 0, stream>>>(
        x, Wi_e, Wh_e, bi_e, bhn_e, hx, enc_h,
        eps, Wi_d, Wh_d, bhn_d, W_shift, b_shift, W_lsc, b_lsc,
        W_pi, b_pi, W_mu, b_mu, W_ls, b_ls,
        gi, out, dec_h, dec_pred, enc_t0, dec_t0, Tc);
    if (k < Nc) gemm_gi<<<gg, 256, 0, stream>>>(hx, Wi_d, bi_d, gi, Tc);
  }
}

// Round 8
// 6230.133 us; speedup vs baseline: 2.2750x; 2.2750x over previous
//
#include <hip/hip_runtime.h>
#include <hip/hip_fp16.h>

#define Tn 4096
#define Bn 128
#define Hn 128
#define G3 384
#define NTH 448        // 7 waves: waves 0-5 matvec/gates, wave 6 heads+coupling

typedef unsigned short u16;
typedef unsigned int u32;
typedef _Float16 f16;
typedef _Float16 h2 __attribute__((ext_vector_type(2)));

__device__ __forceinline__ float sigm(float v) { return 1.f / (1.f + __expf(-v)); }
__device__ __forceinline__ float tanh_fast(float v) {
  v = fminf(fmaxf(v, -15.f), 15.f);
  float e = __expf(-2.f * v);
  return (1.f - e) / (1.f + e);
}
__device__ __forceinline__ u16 f2h(float f) { return __half_as_ushort(__float2half(f)); }
__device__ __forceinline__ float h2f(u16 u) { return __half2float(__ushort_as_half(u)); }
__device__ __forceinline__ h2 bch2(u32 v) { union { u32 u; h2 h; } t; t.u = v; return t.h; }
__device__ __forceinline__ u32 bcu32(h2 v) { union { u32 u; h2 h; } t; t.h = v; return t.u; }
__device__ __forceinline__ float fdot2f(h2 a, h2 b, float c) {
  return __builtin_amdgcn_fdot2(a, b, c, false);
}

// ============ combo: blocks 0..127 = encoder, 128..255 = decoder ============
// h lives packed-f16 in LDS (256 B): matvec = 16 uniform ds_read_b128 + 64
// v_dot2_f32_f16 per lane. Gate threads keep the fp32 master h in-register.
__global__ __launch_bounds__(NTH, 1) void combo_kernel(
    const float* __restrict__ x, const float* __restrict__ Wi_e,
    const float* __restrict__ Wh_e, const float* __restrict__ bi_e,
    const float* __restrict__ bhn_e, u16* __restrict__ hx,
    float* __restrict__ enc_h,
    const float* __restrict__ eps, const float* __restrict__ Wi_d,
    const float* __restrict__ Wh_d, const float* __restrict__ bhn_d,
    const float* __restrict__ W_shift, const float* __restrict__ b_shift,
    const float* __restrict__ W_lsc, const float* __restrict__ b_lsc,
    const float* __restrict__ W_pi, const float* __restrict__ b_pi,
    const float* __restrict__ W_mu, const float* __restrict__ b_mu,
    const float* __restrict__ W_ls, const float* __restrict__ b_ls,
    const u16* __restrict__ gi_pre, float* __restrict__ out,
    float* __restrict__ dec_h, float* __restrict__ dec_pred,
    int enc_t0, int dec_t0, int Tc)
{
  const int j = threadIdx.x;
  __shared__ __align__(16) f16 Xp[Hn];          // packed f16 h
  __shared__ __align__(16) float g2[512];
  __shared__ __align__(16) u32 hwlp[17 * 68];   // head weights packed f16x2
  __shared__ float hbias_l[20];
  __shared__ float pred_s;
  const int bid = blockIdx.x;
  const int jj = (j < 384) ? j : 0;

  if (bid < Bn) {
    // ---------------------------- encoder role ----------------------------
    if (enc_t0 < 0) return;
    const int b = bid, t0 = enc_t0;
    // packed recurrent weights: wp[k] = (Wh[2k][j], Wh[2k+1][j]) as f16x2
    h2 wp[64];
#pragma unroll
    for (int k = 0; k < 64; ++k) {
      h2 t; t.x = (f16)Wh_e[(2 * k) * G3 + jj]; t.y = (f16)Wh_e[(2 * k + 1) * G3 + jj];
      wp[k] = t;
    }
    float wie = 0.f, bie = 0.f, bhn = 0.f, hm = 0.f;
    if (j < 384) { wie = Wi_e[j]; bie = bi_e[j]; }
    if (j < Hn) {
      bhn = bhn_e[j];
      hm = (t0 == 0) ? 0.f : enc_h[(long)b * Hn + j];
      Xp[j] = (f16)hm;
    }
    __syncthreads();
    const float* xrow = x + (long)b * Tn;
    u16* hxrow = hx + (long)b * Tc * Hn;
    float xt = xrow[Tn - 1 - t0];
    for (int tt = 0; tt < Tc; ++tt) {
      const int t = t0 + tt;
      const int tnext = (t + 1 < Tn) ? (t + 1) : (Tn - 1);
      float xnext = xrow[Tn - 1 - tnext];
      if (j < 384) {
        const uint4* hp = (const uint4*)Xp;
        float a0 = 0.f, a1 = 0.f, a2 = 0.f, a3 = 0.f;
#pragma unroll
        for (int q = 0; q < 16; ++q) {
          uint4 hv = hp[q];
          a0 = fdot2f(bch2(hv.x), wp[4 * q + 0], a0);
          a1 = fdot2f(bch2(hv.y), wp[4 * q + 1], a1);
          a2 = fdot2f(bch2(hv.z), wp[4 * q + 2], a2);
          a3 = fdot2f(bch2(hv.w), wp[4 * q + 3], a3);
        }
        float gh = (a0 + a1) + (a2 + a3);
        float gi = fmaf(xt, wie, bie);
        if (j < 256) g2[j] = gh + gi;          // r,z complete pre-activations
        else { g2[j] = gh; g2[j + 128] = gi; } // hn raw, inn raw
      }
      __syncthreads();
      if (j < Hn) {
        float r = sigm(g2[j]);
        float z = sigm(g2[128 + j]);
        float n = tanh_fast(g2[384 + j] + r * (g2[256 + j] + bhn));
        float hn2 = (1.f - z) * n + z * hm;
        hm = hn2;
        Xp[j] = (f16)hn2;
        hxrow[(long)tt * Hn + j] = f2h(hn2);
      }
      xt = xnext;
      __syncthreads();
    }
    if (j < Hn) enc_h[(long)b * Hn + j] = hm;
  } else {
    // ---------------------------- decoder role ----------------------------
    if (dec_t0 < 0) return;
    const int b = bid - Bn, t0 = dec_t0;
    h2 wp[64];
#pragma unroll
    for (int k = 0; k < 64; ++k) {
      h2 t; t.x = (f16)Wh_d[(2 * k) * G3 + jj]; t.y = (f16)Wh_d[(2 * k + 1) * G3 + jj];
      wp[k] = t;
    }
    float bhn = 0.f, wr0 = 0.f, wz0 = 0.f, wn0 = 0.f, hm = 0.f;
    if (j < Hn) {
      bhn = bhn_d[j];
      wr0 = Wi_d[j];           // Wi_d row 0: pred coefficients
      wz0 = Wi_d[128 + j];
      wn0 = Wi_d[256 + j];
      hm = (t0 == 0) ? 0.f : dec_h[(long)b * Hn + j];
      Xp[j] = (f16)hm;
    }
    // stage head weights packed f16x2: hwlp[o*68+k2] = (W[o][2k2], W[o][2k2+1])
    for (int idx = j; idx < 17 * 64; idx += NTH) {
      int o = idx >> 6, k2 = idx & 63;
      int ka = 2 * k2, kb = 2 * k2 + 1;
      float wa, wb;
      if (o == 0) { wa = W_shift[ka]; wb = W_shift[kb]; }
      else if (o == 1) { wa = W_lsc[ka]; wb = W_lsc[kb]; }
      else if (o < 7) { wa = W_pi[ka * 5 + o - 2]; wb = W_pi[kb * 5 + o - 2]; }
      else if (o < 12) { wa = W_mu[ka * 5 + o - 7]; wb = W_mu[kb * 5 + o - 7]; }
      else { wa = W_ls[ka * 5 + o - 12]; wb = W_ls[kb * 5 + o - 12]; }
      h2 t; t.x = (f16)wa; t.y = (f16)wb;
      hwlp[o * 68 + k2] = bcu32(t);
    }
    if (j < 17)
      hbias_l[j] = (j == 0) ? b_shift[0] : (j == 1) ? b_lsc[0] : (j < 7) ? b_pi[j - 2]
                 : (j < 12) ? b_mu[j - 7] : b_ls[j - 12];
    float predreg = (t0 == 0) ? 0.f : dec_pred[b];
    if (j == 384) pred_s = predreg;
    const u16* girow = gi_pre + (long)b * Tc * G3 + jj;
    const float* erow = eps + (long)b * Tn;
    float e_cur = erow[t0];
    u16 gA = 0, gB = 0;
    if (j < 384) { gA = girow[0]; gB = girow[(Tc > 1) ? G3 : 0]; }
    __syncthreads();
    const int lane = j - 384;            // wave-6 lane (valid when j>=384)
    const int ho = lane >> 1, hs = lane & 1;
    float* outlp = out + (long)b * Tn + t0;
    float* outpr = out + (long)Bn * Tn + (long)b * Tn + t0;
    // slot i: [waves0-5: matvec(i)] || [wave6: heads+coupling(i-1)] ; B1 ; gates(i) ; B2
    for (int i = 0; i <= Tc; ++i) {
      u16 gC = 0; float e_next = 0.f;
      if (j < 384 && i < Tc) {
        int ip = (i + 2 < Tc) ? i + 2 : Tc - 1;
        gC = girow[(long)ip * G3];       // prefetch 2 ahead
      }
      if (j >= 384 && i < Tc) e_next = erow[t0 + i];
      if (j < 384) {
        if (i < Tc) {
          const uint4* hp = (const uint4*)Xp;
          float a0 = 0.f, a1 = 0.f, a2 = 0.f, a3 = 0.f;
#pragma unroll
          for (int q = 0; q < 16; ++q) {
            uint4 hv = hp[q];
            a0 = fdot2f(bch2(hv.x), wp[4 * q + 0], a0);
            a1 = fdot2f(bch2(hv.y), wp[4 * q + 1], a1);
            a2 = fdot2f(bch2(hv.z), wp[4 * q + 2], a2);
            a3 = fdot2f(bch2(hv.w), wp[4 * q + 3], a3);
          }
          float gh = (a0 + a1) + (a2 + a3);
          float gipre = h2f(gA);         // input-projection part WITHOUT pred term
          if (j < 256) g2[j] = gh + gipre;
          else { g2[j] = gh; g2[j + 128] = gipre; }
        }
      } else if (i >= 1) {
        // ---- heads for step i-1 (2 lanes per head; packed fdot2) ----
        float p = 0.f;
        if (lane < 34) {
          const uint4* hp4 = (const uint4*)Xp;
          const uint4* wr4 = (const uint4*)&hwlp[ho * 68 + hs * 32];
#pragma unroll
          for (int q = 0; q < 8; ++q) {
            uint4 hv = hp4[hs * 8 + q];
            uint4 wv = wr4[q];
            p = fdot2f(bch2(hv.x), bch2(wv.x), p);
            p = fdot2f(bch2(hv.y), bch2(wv.y), p);
            p = fdot2f(bch2(hv.z), bch2(wv.z), p);
            p = fdot2f(bch2(hv.w), bch2(wv.w), p);
          }
        }
        p += __shfl_xor(p, 1);           // combine the two half-dots
        float pb = p + hbias_l[lane < 34 ? ho : 0];
        // redistribute to coupling lanes (octet lanes 0-7 use lj2 = lane&7)
        const int lj2 = lane & 7;
        float pi_ = __shfl(pb, 4 + 2 * lj2);   // head 2+k
        float mu_ = __shfl(pb, 14 + 2 * lj2);  // head 7+k
        float ls_ = __shfl(pb, 24 + 2 * lj2);  // head 12+k
        float shiftv = __shfl(pb, 0);          // head 0
        float lscv = __shfl(pb, 2);            // head 1
        // ---- linear-domain mixture-logistic coupling ----
        const bool valid = (lane < 5);
        const float e = e_cur;
        float wexp = valid ? __expf(pi_) : 0.f;
        float zz = (e - mu_) * __expf(-ls_);
        float u = __expf(-fabsf(zz));
        float d = 1.f / (1.f + u);
        float sigp = (zz >= 0.f) ? d : u * d;        // sigmoid(z)
        float sigq = (zz >= 0.f) ? u * d : d;        // sigmoid(-z)
        float pdfl = u * d * d * __expf(-ls_);       // logistic pdf
        float c = wexp * sigp, m = wexp * sigq, pp = wexp * pdfl, S = wexp;
        c += __shfl_xor(c, 1, 8); m += __shfl_xor(m, 1, 8);
        pp += __shfl_xor(pp, 1, 8); S += __shfl_xor(S, 1, 8);
        c += __shfl_xor(c, 2, 8); m += __shfl_xor(m, 2, 8);
        pp += __shfl_xor(pp, 2, 8); S += __shfl_xor(S, 2, 8);
        c += __shfl_xor(c, 4, 8); m += __shfl_xor(m, 4, 8);
        pp += __shfl_xor(pp, 4, 8); S += __shfl_xor(S, 4, 8);
        if (lane == 0) {
          float logc = __logf(c), logm = __logf(m);
          float val = logc - logm;                       // logit(CDF)
          float ljac = __logf(pp) + __logf(S) - logc - logm;
          float prednew = fmaf(val, __expf(lscv), shiftv);
          float sp = fmaxf(-e, 0.f) + log1pf(__expf(-fabsf(e)));  // softplus(-e)
          float logp = (-e - 2.f * sp) - lscv - ljac;
          outlp[i - 1] = logp;
          outpr[i - 1] = prednew;
          pred_s = prednew;
          predreg = prednew;
        }
      }
      __syncthreads();                                   // B1
      if (j < Hn && i < Tc) {
        float pred = pred_s;
        float r = sigm(fmaf(pred, wr0, g2[j]));
        float z = sigm(fmaf(pred, wz0, g2[128 + j]));
        float n = tanh_fast(fmaf(pred, wn0, g2[384 + j]) + r * (g2[256 + j] + bhn));
        float hn2 = (1.f - z) * n + z * hm;
        hm = hn2;
        Xp[j] = (f16)hn2;
      }
      __syncthreads();                                   // B2
      gA = gB; gB = gC; e_cur = e_next;
    }
    if (j < Hn) dec_h[(long)b * Hn + j] = hm;
    if (j == 384) dec_pred[b] = predreg;
  }
}

// ------- GEMM: gi_pre[row,:] = hx[row,:] @ Wi_d[1:,:] + bi_d  (fp32 acc) -------
__global__ __launch_bounds__(256) void gemm_gi(
    const u16* __restrict__ A, const float* __restrict__ Wi_d,
    const float* __restrict__ bi_d, u16* __restrict__ C)
{
  __shared__ __align__(16) float As[16][64];  // [k][m]
  __shared__ __align__(16) float Ws[16][64];  // [k][n]
  const int tid = threadIdx.x;
  const long m0 = (long)blockIdx.x * 64;
  const int n0 = blockIdx.y * 64;
  const int tx = tid & 15, ty = tid >> 4;
  const int am = tid >> 2, ak = (tid & 3) * 4;
  const int wk = tid >> 4, wn = (tid & 15) * 4;
  float acc[4][4] = {};
  for (int k0 = 0; k0 < Hn; k0 += 16) {
    uint2 a2v = *(const uint2*)(A + (m0 + am) * Hn + k0 + ak);
    float4 w4 = *(const float4*)(Wi_d + (long)(1 + k0 + wk) * G3 + n0 + wn);
    __syncthreads();
    As[ak + 0][am] = h2f((u16)(a2v.x & 0xffffu));
    As[ak + 1][am] = h2f((u16)(a2v.x >> 16));
    As[ak + 2][am] = h2f((u16)(a2v.y & 0xffffu));
    As[ak + 3][am] = h2f((u16)(a2v.y >> 16));
    *(float4*)&Ws[wk][wn] = w4;
    __syncthreads();
#pragma unroll
    for (int kk = 0; kk < 16; ++kk) {
      float4 av = *(const float4*)&As[kk][ty * 4];
      float4 wv = *(const float4*)&Ws[kk][tx * 4];
      float ar[4] = {av.x, av.y, av.z, av.w};
      float wr[4] = {wv.x, wv.y, wv.z, wv.w};
#pragma unroll
      for (int i = 0; i < 4; ++i)
#pragma unroll
        for (int jj = 0; jj < 4; ++jj) acc[i][jj] = fmaf(ar[i], wr[jj], acc[i][jj]);
    }
  }
  const float4 bb = *(const float4*)(bi_d + n0 + tx * 4);
  const float br[4] = {bb.x, bb.y, bb.z, bb.w};
#pragma unroll
  for (int i = 0; i < 4; ++i) {
    long row = m0 + ty * 4 + i;
    u32 lo = (u32)f2h(acc[i][0] + br[0]) | ((u32)f2h(acc[i][1] + br[1]) << 16);
    u32 hi = (u32)f2h(acc[i][2] + br[2]) | ((u32)f2h(acc[i][3] + br[3]) << 16);
    uint2 o; o.x = lo; o.y = hi;
    *(uint2*)(C + row * G3 + n0 + tx * 4) = o;
  }
}

extern "C" void kernel_launch(void* const* d_in, const int* in_sizes, int n_in,
                              void* d_out, int out_size, void* d_ws, size_t ws_size,
                              hipStream_t stream) {
  const float* x = (const float*)d_in[1];
  const float* eps = (const float*)d_in[2];
  const float* Wi_e = (const float*)d_in[3];
  const float* Wh_e = (const float*)d_in[4];
  const float* bi_e = (const float*)d_in[5];
  const float* bhn_e = (const float*)d_in[6];
  const float* Wi_d = (const float*)d_in[7];
  const float* Wh_d = (const float*)d_in[8];
  const float* bi_d = (const float*)d_in[9];
  const float* bhn_d = (const float*)d_in[10];
  const float* W_shift = (const float*)d_in[11];
  const float* b_shift = (const float*)d_in[12];
  const float* W_lsc = (const float*)d_in[13];
  const float* b_lsc = (const float*)d_in[14];
  const float* W_pi = (const float*)d_in[15];
  const float* b_pi = (const float*)d_in[16];
  const float* W_mu = (const float*)d_in[17];
  const float* b_mu = (const float*)d_in[18];
  const float* W_ls = (const float*)d_in[19];
  const float* b_ls = (const float*)d_in[20];
  float* out = (float*)d_out;

  const size_t stateB = (size_t)(2 * Bn * Hn + Bn) * sizeof(float);
  const size_t stateAl = (stateB + 255) & ~(size_t)255;
  int Tc = 512;  // 8 chunks: enc(k) || dec(k-1) pipeline
  while (Tc > 8 && stateAl + (size_t)Bn * Tc * (Hn + G3) * 2 > ws_size) Tc >>= 1;
  if (stateAl + (size_t)Bn * Tc * (Hn + G3) * 2 > ws_size) return;

  float* enc_h = (float*)d_ws;
  float* dec_h = enc_h + (size_t)Bn * Hn;
  float* dec_pred = dec_h + (size_t)Bn * Hn;
  u16* hx = (u16*)((char*)d_ws + stateAl);
  u16* gi = hx + (size_t)Bn * Tc * Hn;

  const int Nc = Tn / Tc;
  const dim3 gg((unsigned)(((size_t)Bn * Tc) / 64), G3 / 64);
  for (int k = 0; k <= Nc; ++k) {
    int enc_t0 = (k < Nc) ? k * Tc : -1;
    int dec_t0 = (k >= 1) ? (k - 1) * Tc : -1;
    combo_kernel<<<2 * Bn, NTH, 0, stream>>>(
        x, Wi_e, Wh_e, bi_e, bhn_e, hx, enc_h,
        eps, Wi_d, Wh_d, bhn_d, W_shift, b_shift, W_lsc, b_lsc,
        W_pi, b_pi, W_mu, b_mu, W_ls, b_ls,
        gi, out, dec_h, dec_pred, enc_t0, dec_t0, Tc);
    if (k < Nc) gemm_gi<<<gg, 256, 0, stream>>>(hx, Wi_d, bi_d, gi);
  }
}

// Round 9
// 5792.558 us; speedup vs baseline: 2.4468x; 1.0755x over previous
//
#include <hip/hip_runtime.h>
#include <hip/hip_fp16.h>

#define Tn 4096
#define Bn 128
#define Hn 128
#define G3 384
#define NTH 448        // 7 waves: waves 0-5 matvec/gates, wave 6 heads+coupling

typedef unsigned short u16;
typedef unsigned int u32;
typedef _Float16 f16;
typedef _Float16 h2 __attribute__((ext_vector_type(2)));

__device__ __forceinline__ float sigm(float v) { return 1.f / (1.f + __expf(-v)); }
__device__ __forceinline__ float tanh_fast(float v) {
  v = fminf(fmaxf(v, -15.f), 15.f);
  float e = __expf(-2.f * v);
  return (1.f - e) / (1.f + e);
}
__device__ __forceinline__ u16 f2h(float f) { return __half_as_ushort(__float2half(f)); }
__device__ __forceinline__ float h2f(u16 u) { return __half2float(__ushort_as_half(u)); }
__device__ __forceinline__ h2 bch2(u32 v) { union { u32 u; h2 h; } t; t.u = v; return t.h; }
__device__ __forceinline__ u32 bcu32(h2 v) { union { u32 u; h2 h; } t; t.h = v; return t.u; }
__device__ __forceinline__ float fdot2f(h2 a, h2 b, float c) {
  return __builtin_amdgcn_fdot2(a, b, c, false);
}

// ============ combo: blocks 0..127 = encoder, 128..255 = decoder ============
// All per-slot global I/O is batched into per-8-slot vector ops so the
// compiler's vmcnt(0) drain before each __syncthreads is paid once per 8 slots.
__global__ __launch_bounds__(NTH, 1) void combo_kernel(
    const float* __restrict__ x, const float* __restrict__ Wi_e,
    const float* __restrict__ Wh_e, const float* __restrict__ bi_e,
    const float* __restrict__ bhn_e, u16* __restrict__ hx,
    float* __restrict__ enc_h,
    const float* __restrict__ eps, const float* __restrict__ Wi_d,
    const float* __restrict__ Wh_d, const float* __restrict__ bhn_d,
    const float* __restrict__ W_shift, const float* __restrict__ b_shift,
    const float* __restrict__ W_lsc, const float* __restrict__ b_lsc,
    const float* __restrict__ W_pi, const float* __restrict__ b_pi,
    const float* __restrict__ W_mu, const float* __restrict__ b_mu,
    const float* __restrict__ W_ls, const float* __restrict__ b_ls,
    const u16* __restrict__ gi2, float* __restrict__ out,
    float* __restrict__ dec_h, float* __restrict__ dec_pred,
    int enc_t0, int dec_t0, int Tc)
{
  const int j = threadIdx.x;
  __shared__ __align__(16) f16 Xp[Hn];          // packed f16 h
  __shared__ __align__(16) float g2[512];
  __shared__ __align__(16) u32 hwlp[17 * 68];   // head weights packed f16x2
  __shared__ float hbias_l[20];
  __shared__ float pred_s;
  const int bid = blockIdx.x;
  const int jj = (j < 384) ? j : 0;

  if (bid < Bn) {
    // ---------------------------- encoder role ----------------------------
    if (enc_t0 < 0) return;
    const int b = bid, t0 = enc_t0;
    h2 wp[64];
#pragma unroll
    for (int k = 0; k < 64; ++k) {
      h2 t; t.x = (f16)Wh_e[(2 * k) * G3 + jj]; t.y = (f16)Wh_e[(2 * k + 1) * G3 + jj];
      wp[k] = t;
    }
    float wie = 0.f, bie = 0.f, bhn = 0.f, hm = 0.f;
    if (j < 384) { wie = Wi_e[j]; bie = bi_e[j]; }
    if (j < Hn) {
      bhn = bhn_e[j];
      hm = (t0 == 0) ? 0.f : enc_h[(long)b * Hn + j];
      Xp[j] = (f16)hm;
    }
    const float* xrow = x + (long)b * Tn;
    u16* hxrow2 = hx + ((long)b * Hn + (j < Hn ? j : 0)) * Tc;
    // group-0 x batch: x(i=u) = xrow[Tn-1-t0-u], elem (7-u) of [base..base+7]
    float xc0, xc1, xc2, xc3, xc4, xc5, xc6, xc7;
    {
      int base = Tn - 8 - t0; if (base < 0) base = 0;
      float4 v0 = *(const float4*)(xrow + base), v1 = *(const float4*)(xrow + base + 4);
      xc0 = v1.w; xc1 = v1.z; xc2 = v1.y; xc3 = v1.x;
      xc4 = v0.w; xc5 = v0.z; xc6 = v0.y; xc7 = v0.x;
    }
    __syncthreads();
    for (int i8 = 0; i8 < Tc; i8 += 8) {
      int nbase = Tn - 8 - t0 - (i8 + 8); if (nbase < 0) nbase = 0;
      float4 nv0 = *(const float4*)(xrow + nbase);
      float4 nv1 = *(const float4*)(xrow + nbase + 4);
      u32 hb0_ = 0, hb1_ = 0, hb2_ = 0, hb3_ = 0;
#pragma unroll
      for (int u = 0; u < 8; ++u) {
        const float xt = (u == 0) ? xc0 : (u == 1) ? xc1 : (u == 2) ? xc2
                        : (u == 3) ? xc3 : (u == 4) ? xc4 : (u == 5) ? xc5
                        : (u == 6) ? xc6 : xc7;
        if (j < 384) {
          const uint4* hp = (const uint4*)Xp;
          float a0 = 0.f, a1 = 0.f, a2 = 0.f, a3 = 0.f;
#pragma unroll
          for (int q = 0; q < 16; ++q) {
            uint4 hv = hp[q];
            a0 = fdot2f(bch2(hv.x), wp[4 * q + 0], a0);
            a1 = fdot2f(bch2(hv.y), wp[4 * q + 1], a1);
            a2 = fdot2f(bch2(hv.z), wp[4 * q + 2], a2);
            a3 = fdot2f(bch2(hv.w), wp[4 * q + 3], a3);
          }
          float gh = (a0 + a1) + (a2 + a3);
          float gi = fmaf(xt, wie, bie);
          if (j < 256) g2[j] = gh + gi;
          else { g2[j] = gh; g2[j + 128] = gi; }
        }
        __syncthreads();
        if (j < Hn) {
          float r = sigm(g2[j]);
          float z = sigm(g2[128 + j]);
          float n = tanh_fast(g2[384 + j] + r * (g2[256 + j] + bhn));
          float hn2 = (1.f - z) * n + z * hm;
          hm = hn2;
          Xp[j] = (f16)hn2;
          u16 hv = f2h(hn2);
          if (u == 0) hb0_ = hv; else if (u == 1) hb0_ |= ((u32)hv << 16);
          else if (u == 2) hb1_ = hv; else if (u == 3) hb1_ |= ((u32)hv << 16);
          else if (u == 4) hb2_ = hv; else if (u == 5) hb2_ |= ((u32)hv << 16);
          else if (u == 6) hb3_ = hv; else hb3_ |= ((u32)hv << 16);
        }
        __syncthreads();
      }
      if (j < Hn) {
        uint4 o; o.x = hb0_; o.y = hb1_; o.z = hb2_; o.w = hb3_;
        *(uint4*)(hxrow2 + i8) = o;
      }
      xc0 = nv1.w; xc1 = nv1.z; xc2 = nv1.y; xc3 = nv1.x;
      xc4 = nv0.w; xc5 = nv0.z; xc6 = nv0.y; xc7 = nv0.x;
    }
    if (j < Hn) enc_h[(long)b * Hn + j] = hm;
  } else {
    // ---------------------------- decoder role ----------------------------
    if (dec_t0 < 0) return;
    const int b = bid - Bn, t0 = dec_t0;
    h2 wp[64];
#pragma unroll
    for (int k = 0; k < 64; ++k) {
      h2 t; t.x = (f16)Wh_d[(2 * k) * G3 + jj]; t.y = (f16)Wh_d[(2 * k + 1) * G3 + jj];
      wp[k] = t;
    }
    float bhn = 0.f, wr0 = 0.f, wz0 = 0.f, wn0 = 0.f, hm = 0.f;
    if (j < Hn) {
      bhn = bhn_d[j];
      wr0 = Wi_d[j];
      wz0 = Wi_d[128 + j];
      wn0 = Wi_d[256 + j];
      hm = (t0 == 0) ? 0.f : dec_h[(long)b * Hn + j];
      Xp[j] = (f16)hm;
    }
    for (int idx = j; idx < 17 * 64; idx += NTH) {
      int o = idx >> 6, k2 = idx & 63;
      int ka = 2 * k2, kb = 2 * k2 + 1;
      float wa, wb;
      if (o == 0) { wa = W_shift[ka]; wb = W_shift[kb]; }
      else if (o == 1) { wa = W_lsc[ka]; wb = W_lsc[kb]; }
      else if (o < 7) { wa = W_pi[ka * 5 + o - 2]; wb = W_pi[kb * 5 + o - 2]; }
      else if (o < 12) { wa = W_mu[ka * 5 + o - 7]; wb = W_mu[kb * 5 + o - 7]; }
      else { wa = W_ls[ka * 5 + o - 12]; wb = W_ls[kb * 5 + o - 12]; }
      h2 t; t.x = (f16)wa; t.y = (f16)wb;
      hwlp[o * 68 + k2] = bcu32(t);
    }
    if (j < 17)
      hbias_l[j] = (j == 0) ? b_shift[0] : (j == 1) ? b_lsc[0] : (j < 7) ? b_pi[j - 2]
                 : (j < 12) ? b_mu[j - 7] : b_ls[j - 12];
    float predreg = (t0 == 0) ? 0.f : dec_pred[b];
    if (j == 384) pred_s = predreg;
    const u16* girow2 = gi2 + ((long)b * G3 + jj) * Tc;
    const float* erow = eps + (long)b * Tn;
    uint4 gA4 = {0, 0, 0, 0};
    float ep = 0.f, ec0 = 0, ec1 = 0, ec2 = 0, ec3 = 0, ec4 = 0, ec5 = 0, ec6 = 0, ec7 = 0;
    if (j < 384) {
      gA4 = *(const uint4*)(girow2);
    } else {
      float4 v0 = *(const float4*)(erow + t0), v1 = *(const float4*)(erow + t0 + 4);
      ec0 = v0.x; ec1 = v0.y; ec2 = v0.z; ec3 = v0.w;
      ec4 = v1.x; ec5 = v1.y; ec6 = v1.z; ec7 = v1.w;
    }
    float lp0 = 0, lp1 = 0, lp2 = 0, lp3 = 0, lp4 = 0, lp5 = 0, lp6 = 0, lp7 = 0;
    float pr0 = 0, pr1 = 0, pr2 = 0, pr3 = 0, pr4 = 0, pr5 = 0, pr6 = 0, pr7 = 0;
    __syncthreads();
    const int lane = j - 384;
    const int ho = lane >> 1, hs = lane & 1;
    float* outlp = out + (long)b * Tn + t0;
    float* outpr = out + (long)Bn * Tn + (long)b * Tn + t0;

    // heads + coupling for the step whose h is currently in Xp; all wave-6
    // lanes participate (shuffles); result valid on lane 0.
    auto couple = [&](float e) -> float2 {
      float p = 0.f;
      if (lane < 34) {
        const uint4* hp4 = (const uint4*)Xp;
        const uint4* wr4 = (const uint4*)&hwlp[ho * 68 + hs * 32];
#pragma unroll
        for (int q = 0; q < 8; ++q) {
          uint4 hv = hp4[hs * 8 + q];
          uint4 wv = wr4[q];
          p = fdot2f(bch2(hv.x), bch2(wv.x), p);
          p = fdot2f(bch2(hv.y), bch2(wv.y), p);
          p = fdot2f(bch2(hv.z), bch2(wv.z), p);
          p = fdot2f(bch2(hv.w), bch2(wv.w), p);
        }
      }
      p += __shfl_xor(p, 1);
      float pb = p + hbias_l[lane < 34 ? ho : 0];
      const int lj2 = lane & 7;
      float pi_ = __shfl(pb, 4 + 2 * lj2);
      float mu_ = __shfl(pb, 14 + 2 * lj2);
      float ls_ = __shfl(pb, 24 + 2 * lj2);
      float shiftv = __shfl(pb, 0);
      float lscv = __shfl(pb, 2);
      const bool valid = (lane < 5);
      float wexp = valid ? __expf(pi_) : 0.f;
      float zz = (e - mu_) * __expf(-ls_);
      float uq = __expf(-fabsf(zz));
      float dq = 1.f / (1.f + uq);
      float sigp = (zz >= 0.f) ? dq : uq * dq;
      float sigq = (zz >= 0.f) ? uq * dq : dq;
      float pdfl = uq * dq * dq * __expf(-ls_);
      float c = wexp * sigp, m = wexp * sigq, pq = wexp * pdfl, S = wexp;
      c += __shfl_xor(c, 1, 8); m += __shfl_xor(m, 1, 8);
      pq += __shfl_xor(pq, 1, 8); S += __shfl_xor(S, 1, 8);
      c += __shfl_xor(c, 2, 8); m += __shfl_xor(m, 2, 8);
      pq += __shfl_xor(pq, 2, 8); S += __shfl_xor(S, 2, 8);
      c += __shfl_xor(c, 4, 8); m += __shfl_xor(m, 4, 8);
      pq += __shfl_xor(pq, 4, 8); S += __shfl_xor(S, 4, 8);
      float logc = __logf(c), logm = __logf(m);
      float val = logc - logm;
      float ljac = __logf(pq) + __logf(S) - logc - logm;
      float prednew = fmaf(val, __expf(lscv), shiftv);
      float sp = fmaxf(-e, 0.f) + log1pf(__expf(-fabsf(e)));
      float logp = (-e - 2.f * sp) - lscv - ljac;
      return make_float2(logp, prednew);
    };

    for (int i8 = 0; i8 < Tc; i8 += 8) {
      uint4 gB4 = {0, 0, 0, 0};
      float4 en0 = {0, 0, 0, 0}, en1 = {0, 0, 0, 0};
      if (j < 384) {
        int gn = i8 + 8; if (gn > Tc - 8) gn = Tc - 8;
        gB4 = *(const uint4*)(girow2 + gn);
      } else {
        int sn = t0 + i8 + 8; if (sn > Tn - 8) sn = Tn - 8;
        en0 = *(const float4*)(erow + sn);
        en1 = *(const float4*)(erow + sn + 4);
      }
#pragma unroll
      for (int u = 0; u < 8; ++u) {
        const int i = i8 + u;
        if (j < 384) {
          const uint4* hp = (const uint4*)Xp;
          float a0 = 0.f, a1 = 0.f, a2 = 0.f, a3 = 0.f;
#pragma unroll
          for (int q = 0; q < 16; ++q) {
            uint4 hv = hp[q];
            a0 = fdot2f(bch2(hv.x), wp[4 * q + 0], a0);
            a1 = fdot2f(bch2(hv.y), wp[4 * q + 1], a1);
            a2 = fdot2f(bch2(hv.z), wp[4 * q + 2], a2);
            a3 = fdot2f(bch2(hv.w), wp[4 * q + 3], a3);
          }
          float gh = (a0 + a1) + (a2 + a3);
          u16 gv = (u == 0) ? (u16)gA4.x : (u == 1) ? (u16)(gA4.x >> 16)
                 : (u == 2) ? (u16)gA4.y : (u == 3) ? (u16)(gA4.y >> 16)
                 : (u == 4) ? (u16)gA4.z : (u == 5) ? (u16)(gA4.z >> 16)
                 : (u == 6) ? (u16)gA4.w : (u16)(gA4.w >> 16);
          float gipre = h2f(gv);
          if (j < 256) g2[j] = gh + gipre;
          else { g2[j] = gh; g2[j + 128] = gipre; }
        } else if (i >= 1) {
          float e = (u == 0) ? ep : (u == 1) ? ec0 : (u == 2) ? ec1 : (u == 3) ? ec2
                  : (u == 4) ? ec3 : (u == 5) ? ec4 : (u == 6) ? ec5 : ec6;
          float2 rr = couple(e);
          if (lane == 0) {
            if (u == 0) { lp7 = rr.x; pr7 = rr.y; }
            else if (u == 1) { lp0 = rr.x; pr0 = rr.y; }
            else if (u == 2) { lp1 = rr.x; pr1 = rr.y; }
            else if (u == 3) { lp2 = rr.x; pr2 = rr.y; }
            else if (u == 4) { lp3 = rr.x; pr3 = rr.y; }
            else if (u == 5) { lp4 = rr.x; pr4 = rr.y; }
            else if (u == 6) { lp5 = rr.x; pr5 = rr.y; }
            else { lp6 = rr.x; pr6 = rr.y; }
            pred_s = rr.y;
            predreg = rr.y;
            if (u == 0 && i8 > 0) {
              *(float4*)(outlp + i8 - 8) = make_float4(lp0, lp1, lp2, lp3);
              *(float4*)(outlp + i8 - 4) = make_float4(lp4, lp5, lp6, lp7);
              *(float4*)(outpr + i8 - 8) = make_float4(pr0, pr1, pr2, pr3);
              *(float4*)(outpr + i8 - 4) = make_float4(pr4, pr5, pr6, pr7);
            }
          }
        }
        __syncthreads();                                 // B1
        if (j < Hn) {
          float pred = pred_s;
          float r = sigm(fmaf(pred, wr0, g2[j]));
          float z = sigm(fmaf(pred, wz0, g2[128 + j]));
          float n = tanh_fast(fmaf(pred, wn0, g2[384 + j]) + r * (g2[256 + j] + bhn));
          float hn2 = (1.f - z) * n + z * hm;
          hm = hn2;
          Xp[j] = (f16)hn2;
        }
        __syncthreads();                                 // B2
      }
      gA4 = gB4;
      if (j >= 384) {
        ep = ec7;
        ec0 = en0.x; ec1 = en0.y; ec2 = en0.z; ec3 = en0.w;
        ec4 = en1.x; ec5 = en1.y; ec6 = en1.z; ec7 = en1.w;
      }
    }
    // trailing slot i = Tc: coupling for step Tc-1 + final batch store
    if (j >= 384) {
      float2 rr = couple(ep);
      if (lane == 0) {
        lp7 = rr.x; pr7 = rr.y; predreg = rr.y;
        *(float4*)(outlp + Tc - 8) = make_float4(lp0, lp1, lp2, lp3);
        *(float4*)(outlp + Tc - 4) = make_float4(lp4, lp5, lp6, lp7);
        *(float4*)(outpr + Tc - 8) = make_float4(pr0, pr1, pr2, pr3);
        *(float4*)(outpr + Tc - 4) = make_float4(pr4, pr5, pr6, pr7);
      }
    }
    if (j < Hn) dec_h[(long)b * Hn + j] = hm;
    if (j == 384) dec_pred[b] = predreg;
  }
}

// ---- GEMM: gi2[b][col][t] = hx[b][:][t]^T @ Wi_d[1:,:] + bi_d  (fp32 acc) ----
// A2 layout: [b][k][tt] ; C2 layout: [b][col][tt]  (both f16, t contiguous)
__global__ __launch_bounds__(256) void gemm_gi(
    const u16* __restrict__ A2, const float* __restrict__ Wi_d,
    const float* __restrict__ bi_d, u16* __restrict__ C2, int Tc)
{
  __shared__ __align__(16) float As[16][64];  // [k][m]
  __shared__ __align__(16) float Ws[16][64];  // [k][n]
  const int tid = threadIdx.x;
  const long m0 = (long)blockIdx.x * 64;      // m = b*Tc + tt
  const int n0 = blockIdx.y * 64;
  const int bb = (int)(m0 / Tc);
  const int tt0 = (int)(m0 - (long)bb * Tc);
  const int tx = tid & 15, ty = tid >> 4;
  const int lk = tid >> 4, lm = (tid & 15) * 4;   // A-load: k row, 4 tt's
  const int wk = tid >> 4, wn = (tid & 15) * 4;
  float acc[4][4] = {};
  for (int k0 = 0; k0 < Hn; k0 += 16) {
    uint2 a2v = *(const uint2*)(A2 + ((long)bb * Hn + k0 + lk) * Tc + tt0 + lm);
    float4 w4 = *(const float4*)(Wi_d + (long)(1 + k0 + wk) * G3 + n0 + wn);
    __syncthreads();
    As[lk][lm + 0] = h2f((u16)(a2v.x & 0xffffu));
    As[lk][lm + 1] = h2f((u16)(a2v.x >> 16));
    As[lk][lm + 2] = h2f((u16)(a2v.y & 0xffffu));
    As[lk][lm + 3] = h2f((u16)(a2v.y >> 16));
    *(float4*)&Ws[wk][wn] = w4;
    __syncthreads();
#pragma unroll
    for (int kk = 0; kk < 16; ++kk) {
      float4 av = *(const float4*)&As[kk][ty * 4];
      float4 wv = *(const float4*)&Ws[kk][tx * 4];
      float ar[4] = {av.x, av.y, av.z, av.w};
      float wr[4] = {wv.x, wv.y, wv.z, wv.w};
#pragma unroll
      for (int i = 0; i < 4; ++i)
#pragma unroll
        for (int jj = 0; jj < 4; ++jj) acc[i][jj] = fmaf(ar[i], wr[jj], acc[i][jj]);
    }
  }
  const float4 bbv = *(const float4*)(bi_d + n0 + tx * 4);
  const float br[4] = {bbv.x, bbv.y, bbv.z, bbv.w};
#pragma unroll
  for (int jj = 0; jj < 4; ++jj) {
    int colc = n0 + tx * 4 + jj;
    u32 lo = (u32)f2h(acc[0][jj] + br[jj]) | ((u32)f2h(acc[1][jj] + br[jj]) << 16);
    u32 hi = (u32)f2h(acc[2][jj] + br[jj]) | ((u32)f2h(acc[3][jj] + br[jj]) << 16);
    uint2 o; o.x = lo; o.y = hi;
    *(uint2*)(C2 + ((long)bb * G3 + colc) * Tc + tt0 + ty * 4) = o;
  }
}

extern "C" void kernel_launch(void* const* d_in, const int* in_sizes, int n_in,
                              void* d_out, int out_size, void* d_ws, size_t ws_size,
                              hipStream_t stream) {
  const float* x = (const float*)d_in[1];
  const float* eps = (const float*)d_in[2];
  const float* Wi_e = (const float*)d_in[3];
  const float* Wh_e = (const float*)d_in[4];
  const float* bi_e = (const float*)d_in[5];
  const float* bhn_e = (const float*)d_in[6];
  const float* Wi_d = (const float*)d_in[7];
  const float* Wh_d = (const float*)d_in[8];
  const float* bi_d = (const float*)d_in[9];
  const float* bhn_d = (const float*)d_in[10];
  const float* W_shift = (const float*)d_in[11];
  const float* b_shift = (const float*)d_in[12];
  const float* W_lsc = (const float*)d_in[13];
  const float* b_lsc = (const float*)d_in[14];
  const float* W_pi = (const float*)d_in[15];
  const float* b_pi = (const float*)d_in[16];
  const float* W_mu = (const float*)d_in[17];
  const float* b_mu = (const float*)d_in[18];
  const float* W_ls = (const float*)d_in[19];
  const float* b_ls = (const float*)d_in[20];
  float* out = (float*)d_out;

  const size_t stateB = (size_t)(2 * Bn * Hn + Bn) * sizeof(float);
  const size_t stateAl = (stateB + 255) & ~(size_t)255;
  int Tc = 512;  // 8 chunks: enc(k) || dec(k-1) pipeline
  while (Tc > 64 && stateAl + (size_t)Bn * Tc * (Hn + G3) * 2 > ws_size) Tc >>= 1;
  if (stateAl + (size_t)Bn * Tc * (Hn + G3) * 2 > ws_size) return;

  float* enc_h = (float*)d_ws;
  float* dec_h = enc_h + (size_t)Bn * Hn;
  float* dec_pred = dec_h + (size_t)Bn * Hn;
  u16* hx = (u16*)((char*)d_ws + stateAl);          // [b][k][t]
  u16* gi = hx + (size_t)Bn * Tc * Hn;              // [b][col][t]

  const int Nc = Tn / Tc;
  const dim3 gg((unsigned)(((size_t)Bn * Tc) / 64), G3 / 64);
  for (int k = 0; k <= Nc; ++k) {
    int enc_t0 = (k < Nc) ? k * Tc : -1;
    int dec_t0 = (k >= 1) ? (k - 1) * Tc : -1;
    combo_kernel<<<2 * Bn, NTH, 0, stream>>>(
        x, Wi_e, Wh_e, bi_e, bhn_e, hx, enc_h,
        eps, Wi_d, Wh_d, bhn_d, W_shift, b_shift, W_lsc, b_lsc,
        W_pi, b_pi, W_mu, b_mu, W_ls, b_ls,
        gi, out, dec_h, dec_pred, enc_t0, dec_t0, Tc);
    if (k < Nc) gemm_gi<<<gg, 256, 0, stream>>>(hx, Wi_d, bi_d, gi, Tc);
  }
}

// Round 10
// 5692.571 us; speedup vs baseline: 2.4898x; 1.0176x over previous
//
#include <hip/hip_runtime.h>
#include <hip/hip_fp16.h>

#define Tn 4096
#define Bn 128
#define Hn 128
#define G3 384
#define NTH 192   // 3 waves: waves 0-1 matvec+gates (in-register), wave 2 heads

typedef unsigned short u16;
typedef unsigned int u32;
typedef _Float16 f16;
typedef _Float16 h2 __attribute__((ext_vector_type(2)));

__device__ __forceinline__ float sigm(float v) { return 1.f / (1.f + __expf(-v)); }
__device__ __forceinline__ float tanh_fast(float v) {
  v = fminf(fmaxf(v, -15.f), 15.f);
  float e = __expf(-2.f * v);
  return (1.f - e) / (1.f + e);
}
__device__ __forceinline__ u16 f2h(float f) { return __half_as_ushort(__float2half(f)); }
__device__ __forceinline__ float h2f(u16 u) { return __half2float(__ushort_as_half(u)); }
__device__ __forceinline__ h2 bch2(u32 v) { union { u32 u; h2 h; } t; t.u = v; return t.h; }
__device__ __forceinline__ float fdot2f(h2 a, h2 b, float c) {
  return __builtin_amdgcn_fdot2(a, b, c, false);
}

// ============ combo: blocks 0..127 = encoder, 128..255 = decoder ============
// Thread j<128 owns column j of ALL THREE gates (r,z,n): 192 fdot2/slot, gates
// combined in-register (no g2 LDS round-trip). Xp double-buffered: enc = 1
// barrier/slot, dec = 2 (pred_s handoff). Wave 2 (dec): heads+coupling with
// head weights in registers.
__global__ __launch_bounds__(NTH, 1) void combo_kernel(
    const float* __restrict__ x, const float* __restrict__ Wi_e,
    const float* __restrict__ Wh_e, const float* __restrict__ bi_e,
    const float* __restrict__ bhn_e, u16* __restrict__ hx,
    float* __restrict__ enc_h,
    const float* __restrict__ eps, const float* __restrict__ Wi_d,
    const float* __restrict__ Wh_d, const float* __restrict__ bhn_d,
    const float* __restrict__ W_shift, const float* __restrict__ b_shift,
    const float* __restrict__ W_lsc, const float* __restrict__ b_lsc,
    const float* __restrict__ W_pi, const float* __restrict__ b_pi,
    const float* __restrict__ W_mu, const float* __restrict__ b_mu,
    const float* __restrict__ W_ls, const float* __restrict__ b_ls,
    const u16* __restrict__ gi2, float* __restrict__ out,
    float* __restrict__ dec_h, float* __restrict__ dec_pred,
    int enc_t0, int dec_t0, int Tc)
{
  const int j = threadIdx.x;
  __shared__ __align__(16) f16 Xp[2][Hn];   // double-buffered packed-f16 h
  __shared__ float pred_s;
  const int bid = blockIdx.x;
  int cur = 0;

  if (bid < Bn) {
    // ---------------------------- encoder role ----------------------------
    if (enc_t0 < 0) return;
    const int b = bid, t0 = enc_t0;
    h2 wr_[64], wz_[64], wn_[64];
    float wieR = 0, wieZ = 0, wieN = 0, bieR = 0, bieZ = 0, bieN = 0;
    float bhn = 0, hm = 0;
    if (j < Hn) {
#pragma unroll
      for (int q = 0; q < 64; ++q) {
        h2 a, bq, c;
        a.x = (f16)Wh_e[(2 * q) * G3 + j];        a.y = (f16)Wh_e[(2 * q + 1) * G3 + j];
        bq.x = (f16)Wh_e[(2 * q) * G3 + 128 + j]; bq.y = (f16)Wh_e[(2 * q + 1) * G3 + 128 + j];
        c.x = (f16)Wh_e[(2 * q) * G3 + 256 + j];  c.y = (f16)Wh_e[(2 * q + 1) * G3 + 256 + j];
        wr_[q] = a; wz_[q] = bq; wn_[q] = c;
      }
      wieR = Wi_e[j]; wieZ = Wi_e[128 + j]; wieN = Wi_e[256 + j];
      bieR = bi_e[j]; bieZ = bi_e[128 + j]; bieN = bi_e[256 + j];
      bhn = bhn_e[j];
      hm = (t0 == 0) ? 0.f : enc_h[(long)b * Hn + j];
      Xp[0][j] = (f16)hm;
    }
    __syncthreads();
    const float* xrow = x + (long)b * Tn;
    u16* hxrow = hx + ((long)b * Hn + (j < Hn ? j : 0)) * Tc;
    for (int i8 = 0; i8 < Tc; i8 += 8) {
      float xc0 = 0, xc1 = 0, xc2 = 0, xc3 = 0, xc4 = 0, xc5 = 0, xc6 = 0, xc7 = 0;
      u32 hb0 = 0, hb1 = 0, hb2 = 0, hb3 = 0;
      if (j < Hn) {
        int base = Tn - 8 - t0 - i8; if (base < 0) base = 0;
        float4 v0 = *(const float4*)(xrow + base);
        float4 v1 = *(const float4*)(xrow + base + 4);
        xc0 = v1.w; xc1 = v1.z; xc2 = v1.y; xc3 = v1.x;
        xc4 = v0.w; xc5 = v0.z; xc6 = v0.y; xc7 = v0.x;
      }
#pragma unroll
      for (int u = 0; u < 8; ++u) {
        if (j < Hn) {
          const uint4* hp = (const uint4*)Xp[cur];
          float a0r = 0, a1r = 0, a0z = 0, a1z = 0, a0n = 0, a1n = 0;
#pragma unroll
          for (int q = 0; q < 16; ++q) {
            uint4 hv = hp[q];
            a0r = fdot2f(bch2(hv.x), wr_[4 * q + 0], a0r);
            a1r = fdot2f(bch2(hv.y), wr_[4 * q + 1], a1r);
            a0r = fdot2f(bch2(hv.z), wr_[4 * q + 2], a0r);
            a1r = fdot2f(bch2(hv.w), wr_[4 * q + 3], a1r);
            a0z = fdot2f(bch2(hv.x), wz_[4 * q + 0], a0z);
            a1z = fdot2f(bch2(hv.y), wz_[4 * q + 1], a1z);
            a0z = fdot2f(bch2(hv.z), wz_[4 * q + 2], a0z);
            a1z = fdot2f(bch2(hv.w), wz_[4 * q + 3], a1z);
            a0n = fdot2f(bch2(hv.x), wn_[4 * q + 0], a0n);
            a1n = fdot2f(bch2(hv.y), wn_[4 * q + 1], a1n);
            a0n = fdot2f(bch2(hv.z), wn_[4 * q + 2], a0n);
            a1n = fdot2f(bch2(hv.w), wn_[4 * q + 3], a1n);
          }
          const float xt = (u == 0) ? xc0 : (u == 1) ? xc1 : (u == 2) ? xc2
                          : (u == 3) ? xc3 : (u == 4) ? xc4 : (u == 5) ? xc5
                          : (u == 6) ? xc6 : xc7;
          float r = sigm((a0r + a1r) + fmaf(xt, wieR, bieR));
          float z = sigm((a0z + a1z) + fmaf(xt, wieZ, bieZ));
          float n = tanh_fast(fmaf(xt, wieN, bieN) + r * ((a0n + a1n) + bhn));
          hm = (1.f - z) * n + z * hm;
          Xp[cur ^ 1][j] = (f16)hm;
          u16 hv16 = f2h(hm);
          if (u == 0) hb0 = hv16; else if (u == 1) hb0 |= ((u32)hv16 << 16);
          else if (u == 2) hb1 = hv16; else if (u == 3) hb1 |= ((u32)hv16 << 16);
          else if (u == 4) hb2 = hv16; else if (u == 5) hb2 |= ((u32)hv16 << 16);
          else if (u == 6) hb3 = hv16; else hb3 |= ((u32)hv16 << 16);
        }
        __syncthreads();
        cur ^= 1;
      }
      if (j < Hn) {
        uint4 o; o.x = hb0; o.y = hb1; o.z = hb2; o.w = hb3;
        *(uint4*)(hxrow + i8) = o;
      }
    }
    if (j < Hn) enc_h[(long)b * Hn + j] = hm;
  } else {
    // ---------------------------- decoder role ----------------------------
    if (dec_t0 < 0) return;
    const int b = bid - Bn, t0 = dec_t0;
    const int lane = j - 128;            // wave-2 lane (valid when j>=128)
    h2 wr_[64], wz_[64], wn_[64];
    h2 wp2[32];
    float wr0 = 0, wz0 = 0, wn0 = 0, bhn = 0, hm = 0;
    float hbias = 0, predreg = 0;
    if (j < Hn) {
#pragma unroll
      for (int q = 0; q < 64; ++q) {
        h2 a, bq, c;
        a.x = (f16)Wh_d[(2 * q) * G3 + j];        a.y = (f16)Wh_d[(2 * q + 1) * G3 + j];
        bq.x = (f16)Wh_d[(2 * q) * G3 + 128 + j]; bq.y = (f16)Wh_d[(2 * q + 1) * G3 + 128 + j];
        c.x = (f16)Wh_d[(2 * q) * G3 + 256 + j];  c.y = (f16)Wh_d[(2 * q + 1) * G3 + 256 + j];
        wr_[q] = a; wz_[q] = bq; wn_[q] = c;
      }
      wr0 = Wi_d[j]; wz0 = Wi_d[128 + j]; wn0 = Wi_d[256 + j];
      bhn = bhn_d[j];
      hm = (t0 == 0) ? 0.f : dec_h[(long)b * Hn + j];
      Xp[0][j] = (f16)hm;
    } else {
      const int ho = lane >> 1, hs = lane & 1;
      if (lane < 34) {
#pragma unroll
        for (int q = 0; q < 32; ++q) {
          int ka = 2 * (hs * 32 + q), kb = ka + 1;
          float wa, wb;
          if (ho == 0) { wa = W_shift[ka]; wb = W_shift[kb]; }
          else if (ho == 1) { wa = W_lsc[ka]; wb = W_lsc[kb]; }
          else if (ho < 7) { wa = W_pi[ka * 5 + ho - 2]; wb = W_pi[kb * 5 + ho - 2]; }
          else if (ho < 12) { wa = W_mu[ka * 5 + ho - 7]; wb = W_mu[kb * 5 + ho - 7]; }
          else { wa = W_ls[ka * 5 + ho - 12]; wb = W_ls[kb * 5 + ho - 12]; }
          h2 t; t.x = (f16)wa; t.y = (f16)wb;
          wp2[q] = t;
        }
        hbias = (ho == 0) ? b_shift[0] : (ho == 1) ? b_lsc[0] : (ho < 7) ? b_pi[ho - 2]
              : (ho < 12) ? b_mu[ho - 7] : b_ls[ho - 12];
      } else {
#pragma unroll
        for (int q = 0; q < 32; ++q) { h2 t; t.x = (f16)0.f; t.y = (f16)0.f; wp2[q] = t; }
      }
      predreg = (t0 == 0) ? 0.f : dec_pred[b];
      if (lane == 0) pred_s = predreg;
    }
    const float* erow = eps + (long)b * Tn;
    const u16* gibase = gi2 + (long)b * G3 * Tc;
    float ep = 0.f;
    float lp0 = 0, lp1 = 0, lp2 = 0, lp3 = 0, lp4 = 0, lp5 = 0, lp6 = 0, lp7 = 0;
    float pr0 = 0, pr1 = 0, pr2 = 0, pr3 = 0, pr4 = 0, pr5 = 0, pr6 = 0, pr7 = 0;
    float* outlp = out + (long)b * Tn + t0;
    float* outpr = out + (long)Bn * Tn + (long)b * Tn + t0;
    __syncthreads();

    // heads + coupling on wave 2 for the h currently in Xc; valid on lane 0.
    auto couple = [&](float e, const f16* Xc) -> float2 {
      const int hs = lane & 1;
      float p = 0.f;
      if (lane < 34) {
        const uint4* hp4 = (const uint4*)Xc;
#pragma unroll
        for (int q = 0; q < 8; ++q) {
          uint4 hv = hp4[hs * 8 + q];
          p = fdot2f(bch2(hv.x), wp2[4 * q + 0], p);
          p = fdot2f(bch2(hv.y), wp2[4 * q + 1], p);
          p = fdot2f(bch2(hv.z), wp2[4 * q + 2], p);
          p = fdot2f(bch2(hv.w), wp2[4 * q + 3], p);
        }
      }
      p += __shfl_xor(p, 1);
      float pb = p + hbias;
      const int lj2 = lane & 7;
      float pi_ = __shfl(pb, 4 + 2 * lj2);
      float mu_ = __shfl(pb, 14 + 2 * lj2);
      float ls_ = __shfl(pb, 24 + 2 * lj2);
      float shiftv = __shfl(pb, 0);
      float lscv = __shfl(pb, 2);
      const bool valid = (lane < 5);
      float wexp = valid ? __expf(pi_) : 0.f;
      float zz = (e - mu_) * __expf(-ls_);
      float uq = __expf(-fabsf(zz));
      float dq = 1.f / (1.f + uq);
      float sigp = (zz >= 0.f) ? dq : uq * dq;
      float sigq = (zz >= 0.f) ? uq * dq : dq;
      float pdfl = uq * dq * dq * __expf(-ls_);
      float c = wexp * sigp, m = wexp * sigq, pq = wexp * pdfl, S = wexp;
      c += __shfl_xor(c, 1, 8); m += __shfl_xor(m, 1, 8);
      pq += __shfl_xor(pq, 1, 8); S += __shfl_xor(S, 1, 8);
      c += __shfl_xor(c, 2, 8); m += __shfl_xor(m, 2, 8);
      pq += __shfl_xor(pq, 2, 8); S += __shfl_xor(S, 2, 8);
      c += __shfl_xor(c, 4, 8); m += __shfl_xor(m, 4, 8);
      pq += __shfl_xor(pq, 4, 8); S += __shfl_xor(S, 4, 8);
      float logc = __logf(c), logm = __logf(m);
      float val = logc - logm;
      float ljac = __logf(pq) + __logf(S) - logc - logm;
      float prednew = fmaf(val, __expf(lscv), shiftv);
      float sp = fmaxf(-e, 0.f) + log1pf(__expf(-fabsf(e)));
      float logp = (-e - 2.f * sp) - lscv - ljac;
      return make_float2(logp, prednew);
    };

    for (int i8 = 0; i8 < Tc; i8 += 8) {
      uint4 gR4 = {0, 0, 0, 0}, gZ4 = {0, 0, 0, 0}, gN4 = {0, 0, 0, 0};
      float ec0 = 0, ec1 = 0, ec2 = 0, ec3 = 0, ec4 = 0, ec5 = 0, ec6 = 0, ec7 = 0;
      if (j < Hn) {
        gR4 = *(const uint4*)(gibase + (long)j * Tc + i8);
        gZ4 = *(const uint4*)(gibase + (long)(128 + j) * Tc + i8);
        gN4 = *(const uint4*)(gibase + (long)(256 + j) * Tc + i8);
      } else {
        float4 v0 = *(const float4*)(erow + t0 + i8);
        float4 v1 = *(const float4*)(erow + t0 + i8 + 4);
        ec0 = v0.x; ec1 = v0.y; ec2 = v0.z; ec3 = v0.w;
        ec4 = v1.x; ec5 = v1.y; ec6 = v1.z; ec7 = v1.w;
      }
#pragma unroll
      for (int u = 0; u < 8; ++u) {
        const int i = i8 + u;
        float ar = 0, az = 0, an = 0;
        if (j < Hn) {
          const uint4* hp = (const uint4*)Xp[cur];
          float a0r = 0, a1r = 0, a0z = 0, a1z = 0, a0n = 0, a1n = 0;
#pragma unroll
          for (int q = 0; q < 16; ++q) {
            uint4 hv = hp[q];
            a0r = fdot2f(bch2(hv.x), wr_[4 * q + 0], a0r);
            a1r = fdot2f(bch2(hv.y), wr_[4 * q + 1], a1r);
            a0r = fdot2f(bch2(hv.z), wr_[4 * q + 2], a0r);
            a1r = fdot2f(bch2(hv.w), wr_[4 * q + 3], a1r);
            a0z = fdot2f(bch2(hv.x), wz_[4 * q + 0], a0z);
            a1z = fdot2f(bch2(hv.y), wz_[4 * q + 1], a1z);
            a0z = fdot2f(bch2(hv.z), wz_[4 * q + 2], a0z);
            a1z = fdot2f(bch2(hv.w), wz_[4 * q + 3], a1z);
            a0n = fdot2f(bch2(hv.x), wn_[4 * q + 0], a0n);
            a1n = fdot2f(bch2(hv.y), wn_[4 * q + 1], a1n);
            a0n = fdot2f(bch2(hv.z), wn_[4 * q + 2], a0n);
            a1n = fdot2f(bch2(hv.w), wn_[4 * q + 3], a1n);
          }
          ar = a0r + a1r; az = a0z + a1z; an = a0n + a1n;
        } else if (i >= 1) {
          float e = (u == 0) ? ep : (u == 1) ? ec0 : (u == 2) ? ec1 : (u == 3) ? ec2
                  : (u == 4) ? ec3 : (u == 5) ? ec4 : (u == 6) ? ec5 : ec6;
          float2 rr = couple(e, Xp[cur]);
          if (lane == 0) {
            if (u == 0) { lp7 = rr.x; pr7 = rr.y; }
            else if (u == 1) { lp0 = rr.x; pr0 = rr.y; }
            else if (u == 2) { lp1 = rr.x; pr1 = rr.y; }
            else if (u == 3) { lp2 = rr.x; pr2 = rr.y; }
            else if (u == 4) { lp3 = rr.x; pr3 = rr.y; }
            else if (u == 5) { lp4 = rr.x; pr4 = rr.y; }
            else if (u == 6) { lp5 = rr.x; pr5 = rr.y; }
            else { lp6 = rr.x; pr6 = rr.y; }
            pred_s = rr.y;
            predreg = rr.y;
            if (u == 0 && i8 > 0) {
              *(float4*)(outlp + i8 - 8) = make_float4(lp0, lp1, lp2, lp3);
              *(float4*)(outlp + i8 - 4) = make_float4(lp4, lp5, lp6, lp7);
              *(float4*)(outpr + i8 - 8) = make_float4(pr0, pr1, pr2, pr3);
              *(float4*)(outpr + i8 - 4) = make_float4(pr4, pr5, pr6, pr7);
            }
          }
        }
        __syncthreads();                                 // B1: pred_s ready
        if (j < Hn) {
          u16 gvr = (u == 0) ? (u16)gR4.x : (u == 1) ? (u16)(gR4.x >> 16)
                  : (u == 2) ? (u16)gR4.y : (u == 3) ? (u16)(gR4.y >> 16)
                  : (u == 4) ? (u16)gR4.z : (u == 5) ? (u16)(gR4.z >> 16)
                  : (u == 6) ? (u16)gR4.w : (u16)(gR4.w >> 16);
          u16 gvz = (u == 0) ? (u16)gZ4.x : (u == 1) ? (u16)(gZ4.x >> 16)
                  : (u == 2) ? (u16)gZ4.y : (u == 3) ? (u16)(gZ4.y >> 16)
                  : (u == 4) ? (u16)gZ4.z : (u == 5) ? (u16)(gZ4.z >> 16)
                  : (u == 6) ? (u16)gZ4.w : (u16)(gZ4.w >> 16);
          u16 gvn = (u == 0) ? (u16)gN4.x : (u == 1) ? (u16)(gN4.x >> 16)
                  : (u == 2) ? (u16)gN4.y : (u == 3) ? (u16)(gN4.y >> 16)
                  : (u == 4) ? (u16)gN4.z : (u == 5) ? (u16)(gN4.z >> 16)
                  : (u == 6) ? (u16)gN4.w : (u16)(gN4.w >> 16);
          float pred = pred_s;
          float r = sigm(ar + h2f(gvr) + pred * wr0);
          float z = sigm(az + h2f(gvz) + pred * wz0);
          float n = tanh_fast(h2f(gvn) + pred * wn0 + r * (an + bhn));
          hm = (1.f - z) * n + z * hm;
          Xp[cur ^ 1][j] = (f16)hm;
        }
        __syncthreads();                                 // B2: Xp(next) ready
        cur ^= 1;
      }
      if (j >= 128) ep = ec7;
    }
    // trailing couple for step Tc-1 + final batch store
    if (j >= 128) {
      float2 rr = couple(ep, Xp[cur]);
      if (lane == 0) {
        lp7 = rr.x; pr7 = rr.y; predreg = rr.y;
        *(float4*)(outlp + Tc - 8) = make_float4(lp0, lp1, lp2, lp3);
        *(float4*)(outlp + Tc - 4) = make_float4(lp4, lp5, lp6, lp7);
        *(float4*)(outpr + Tc - 8) = make_float4(pr0, pr1, pr2, pr3);
        *(float4*)(outpr + Tc - 4) = make_float4(pr4, pr5, pr6, pr7);
      }
    }
    if (j < Hn) dec_h[(long)b * Hn + j] = hm;
    if (j == 128) dec_pred[b] = predreg;
  }
}

// ---- GEMM: gi2[b][col][t] = hx[b][:][t]^T @ Wi_d[1:,:] + bi_d  (fp32 acc) ----
// A2 layout: [b][k][tt] ; C2 layout: [b][col][tt]  (both f16, t contiguous)
__global__ __launch_bounds__(256) void gemm_gi(
    const u16* __restrict__ A2, const float* __restrict__ Wi_d,
    const float* __restrict__ bi_d, u16* __restrict__ C2, int Tc)
{
  __shared__ __align__(16) float As[16][64];  // [k][m]
  __shared__ __align__(16) float Ws[16][64];  // [k][n]
  const int tid = threadIdx.x;
  const long m0 = (long)blockIdx.x * 64;      // m = b*Tc + tt
  const int n0 = blockIdx.y * 64;
  const int bb = (int)(m0 / Tc);
  const int tt0 = (int)(m0 - (long)bb * Tc);
  const int tx = tid & 15, ty = tid >> 4;
  const int lk = tid >> 4, lm = (tid & 15) * 4;   // A-load: k row, 4 tt's
  const int wk = tid >> 4, wn = (tid & 15) * 4;
  float acc[4][4] = {};
  for (int k0 = 0; k0 < Hn; k0 += 16) {
    uint2 a2v = *(const uint2*)(A2 + ((long)bb * Hn + k0 + lk) * Tc + tt0 + lm);
    float4 w4 = *(const float4*)(Wi_d + (long)(1 + k0 + wk) * G3 + n0 + wn);
    __syncthreads();
    As[lk][lm + 0] = h2f((u16)(a2v.x & 0xffffu));
    As[lk][lm + 1] = h2f((u16)(a2v.x >> 16));
    As[lk][lm + 2] = h2f((u16)(a2v.y & 0xffffu));
    As[lk][lm + 3] = h2f((u16)(a2v.y >> 16));
    *(float4*)&Ws[wk][wn] = w4;
    __syncthreads();
#pragma unroll
    for (int kk = 0; kk < 16; ++kk) {
      float4 av = *(const float4*)&As[kk][ty * 4];
      float4 wv = *(const float4*)&Ws[kk][tx * 4];
      float ar[4] = {av.x, av.y, av.z, av.w};
      float wr[4] = {wv.x, wv.y, wv.z, wv.w};
#pragma unroll
      for (int i = 0; i < 4; ++i)
#pragma unroll
        for (int jj = 0; jj < 4; ++jj) acc[i][jj] = fmaf(ar[i], wr[jj], acc[i][jj]);
    }
  }
  const float4 bbv = *(const float4*)(bi_d + n0 + tx * 4);
  const float br[4] = {bbv.x, bbv.y, bbv.z, bbv.w};
#pragma unroll
  for (int jj = 0; jj < 4; ++jj) {
    int colc = n0 + tx * 4 + jj;
    u32 lo = (u32)f2h(acc[0][jj] + br[jj]) | ((u32)f2h(acc[1][jj] + br[jj]) << 16);
    u32 hi = (u32)f2h(acc[2][jj] + br[jj]) | ((u32)f2h(acc[3][jj] + br[jj]) << 16);
    uint2 o; o.x = lo; o.y = hi;
    *(uint2*)(C2 + ((long)bb * G3 + colc) * Tc + tt0 + ty * 4) = o;
  }
}

extern "C" void kernel_launch(void* const* d_in, const int* in_sizes, int n_in,
                              void* d_out, int out_size, void* d_ws, size_t ws_size,
                              hipStream_t stream) {
  const float* x = (const float*)d_in[1];
  const float* eps = (const float*)d_in[2];
  const float* Wi_e = (const float*)d_in[3];
  const float* Wh_e = (const float*)d_in[4];
  const float* bi_e = (const float*)d_in[5];
  const float* bhn_e = (const float*)d_in[6];
  const float* Wi_d = (const float*)d_in[7];
  const float* Wh_d = (const float*)d_in[8];
  const float* bi_d = (const float*)d_in[9];
  const float* bhn_d = (const float*)d_in[10];
  const float* W_shift = (const float*)d_in[11];
  const float* b_shift = (const float*)d_in[12];
  const float* W_lsc = (const float*)d_in[13];
  const float* b_lsc = (const float*)d_in[14];
  const float* W_pi = (const float*)d_in[15];
  const float* b_pi = (const float*)d_in[16];
  const float* W_mu = (const float*)d_in[17];
  const float* b_mu = (const float*)d_in[18];
  const float* W_ls = (const float*)d_in[19];
  const float* b_ls = (const float*)d_in[20];
  float* out = (float*)d_out;

  const size_t stateB = (size_t)(2 * Bn * Hn + Bn) * sizeof(float);
  const size_t stateAl = (stateB + 255) & ~(size_t)255;
  int Tc = 512;  // 8 chunks: enc(k) || dec(k-1) pipeline
  while (Tc > 64 && stateAl + (size_t)Bn * Tc * (Hn + G3) * 2 > ws_size) Tc >>= 1;
  if (stateAl + (size_t)Bn * Tc * (Hn + G3) * 2 > ws_size) return;

  float* enc_h = (float*)d_ws;
  float* dec_h = enc_h + (size_t)Bn * Hn;
  float* dec_pred = dec_h + (size_t)Bn * Hn;
  u16* hx = (u16*)((char*)d_ws + stateAl);          // [b][k][t]
  u16* gi = hx + (size_t)Bn * Tc * Hn;              // [b][col][t]

  const int Nc = Tn / Tc;
  const dim3 gg((unsigned)(((size_t)Bn * Tc) / 64), G3 / 64);
  for (int k = 0; k <= Nc; ++k) {
    int enc_t0 = (k < Nc) ? k * Tc : -1;
    int dec_t0 = (k >= 1) ? (k - 1) * Tc : -1;
    combo_kernel<<<2 * Bn, NTH, 0, stream>>>(
        x, Wi_e, Wh_e, bi_e, bhn_e, hx, enc_h,
        eps, Wi_d, Wh_d, bhn_d, W_shift, b_shift, W_lsc, b_lsc,
        W_pi, b_pi, W_mu, b_mu, W_ls, b_ls,
        gi, out, dec_h, dec_pred, enc_t0, dec_t0, Tc);
    if (k < Nc) gemm_gi<<<gg, 256, 0, stream>>>(hx, Wi_d, bi_d, gi, Tc);
  }
}

// Round 11
// 5622.995 us; speedup vs baseline: 2.5206x; 1.0124x over previous
//
#include <hip/hip_runtime.h>
#include <hip/hip_fp16.h>

#define Tn 4096
#define Bn 128
#define Hn 128
#define G3 384
#define NTH 256  // 4 waves: 0-1 r/z matvec+gates, 2 n-matvec, 3 heads+coupling

typedef unsigned short u16;
typedef unsigned int u32;
typedef _Float16 f16;
typedef _Float16 h2 __attribute__((ext_vector_type(2)));

__device__ __forceinline__ float sigm(float v) { return 1.f / (1.f + __expf(-v)); }
__device__ __forceinline__ float tanh_fast(float v) {
  v = fminf(fmaxf(v, -15.f), 15.f);
  float e = __expf(-2.f * v);
  return (1.f - e) / (1.f + e);
}
__device__ __forceinline__ u16 f2h(float f) { return __half_as_ushort(__float2half(f)); }
__device__ __forceinline__ float h2f(u16 u) { return __half2float(__ushort_as_half(u)); }
__device__ __forceinline__ h2 bch2(u32 v) { union { u32 u; h2 h; } t; t.u = v; return t.h; }
__device__ __forceinline__ float fdot2f(h2 a, h2 b, float c) {
  return __builtin_amdgcn_fdot2(a, b, c, false);
}

// ============ combo: blocks 0..127 = encoder, 128..255 = decoder ============
// Per-thread weight footprint capped at 128 VGPRs (r/z on waves 0-1, n on
// wave 2) so the full working set fits comfortably in registers — no per-slot
// weight reloads. nds[] carries the n-gate dot from wave 2 to the gate threads.
__global__ __launch_bounds__(NTH, 1) void combo_kernel(
    const float* __restrict__ x, const float* __restrict__ Wi_e,
    const float* __restrict__ Wh_e, const float* __restrict__ bi_e,
    const float* __restrict__ bhn_e, u16* __restrict__ hx,
    float* __restrict__ enc_h,
    const float* __restrict__ eps, const float* __restrict__ Wi_d,
    const float* __restrict__ Wh_d, const float* __restrict__ bhn_d,
    const float* __restrict__ W_shift, const float* __restrict__ b_shift,
    const float* __restrict__ W_lsc, const float* __restrict__ b_lsc,
    const float* __restrict__ W_pi, const float* __restrict__ b_pi,
    const float* __restrict__ W_mu, const float* __restrict__ b_mu,
    const float* __restrict__ W_ls, const float* __restrict__ b_ls,
    const u16* __restrict__ gi2, float* __restrict__ out,
    float* __restrict__ dec_h, float* __restrict__ dec_pred,
    int enc_t0, int dec_t0, int Tc)
{
  const int j = threadIdx.x;
  __shared__ __align__(16) f16 Xp[2][Hn];   // double-buffered packed-f16 h
  __shared__ __align__(16) float nds[Hn];   // n-gate dot (Wh_n . h) per col
  __shared__ float pred_s;
  const int bid = blockIdx.x;
  int cur = 0;
  const bool is_enc = bid < Bn;
  if (is_enc) { if (enc_t0 < 0) return; } else { if (dec_t0 < 0) return; }
  const int b = is_enc ? bid : bid - Bn;
  const int t0 = is_enc ? enc_t0 : dec_t0;
  const float* Wh = is_enc ? Wh_e : Wh_d;

  // ---------------- per-wave persistent register state ----------------
  h2 wa_[64], wb_[64];        // waves0-1: r,z col j | wave2: n cols 2l,2l+1
  float hm = 0.f;
  // gate-thread extras (j<128)
  float bhn = 0, wr0 = 0, wz0 = 0, wn0 = 0;
  float wieR = 0, wieZ = 0, wieN = 0, bieR = 0, bieZ = 0, bieN = 0;
  // wave-3 extras
  h2 wp2[32];
  float hbias = 0, predreg = 0;

  if (j < Hn) {
#pragma unroll
    for (int q = 0; q < 64; ++q) {
      h2 a, bq;
      a.x = (f16)Wh[(2 * q) * G3 + j];        a.y = (f16)Wh[(2 * q + 1) * G3 + j];
      bq.x = (f16)Wh[(2 * q) * G3 + 128 + j]; bq.y = (f16)Wh[(2 * q + 1) * G3 + 128 + j];
      wa_[q] = a; wb_[q] = bq;
    }
    if (is_enc) {
      wieR = Wi_e[j]; wieZ = Wi_e[128 + j]; wieN = Wi_e[256 + j];
      bieR = bi_e[j]; bieZ = bi_e[128 + j]; bieN = bi_e[256 + j];
      bhn = bhn_e[j];
      hm = (t0 == 0) ? 0.f : enc_h[(long)b * Hn + j];
    } else {
      wr0 = Wi_d[j]; wz0 = Wi_d[128 + j]; wn0 = Wi_d[256 + j];
      bhn = bhn_d[j];
      hm = (t0 == 0) ? 0.f : dec_h[(long)b * Hn + j];
    }
    Xp[0][j] = (f16)hm;
  } else if (j < 192) {
    const int l = j - 128;              // wave-2 lane: n-gate cols 2l, 2l+1
#pragma unroll
    for (int q = 0; q < 64; ++q) {
      h2 a, bq;
      a.x = (f16)Wh[(2 * q) * G3 + 256 + 2 * l];
      a.y = (f16)Wh[(2 * q + 1) * G3 + 256 + 2 * l];
      bq.x = (f16)Wh[(2 * q) * G3 + 256 + 2 * l + 1];
      bq.y = (f16)Wh[(2 * q + 1) * G3 + 256 + 2 * l + 1];
      wa_[q] = a; wb_[q] = bq;
    }
  } else if (!is_enc) {
    const int lane = j - 192, ho = lane >> 1, hs = lane & 1;
    if (lane < 34) {
#pragma unroll
      for (int q = 0; q < 32; ++q) {
        int ka = 2 * (hs * 32 + q), kb = ka + 1;
        float wva, wvb;
        if (ho == 0) { wva = W_shift[ka]; wvb = W_shift[kb]; }
        else if (ho == 1) { wva = W_lsc[ka]; wvb = W_lsc[kb]; }
        else if (ho < 7) { wva = W_pi[ka * 5 + ho - 2]; wvb = W_pi[kb * 5 + ho - 2]; }
        else if (ho < 12) { wva = W_mu[ka * 5 + ho - 7]; wvb = W_mu[kb * 5 + ho - 7]; }
        else { wva = W_ls[ka * 5 + ho - 12]; wvb = W_ls[kb * 5 + ho - 12]; }
        h2 t; t.x = (f16)wva; t.y = (f16)wvb;
        wp2[q] = t;
      }
      hbias = (ho == 0) ? b_shift[0] : (ho == 1) ? b_lsc[0] : (ho < 7) ? b_pi[ho - 2]
            : (ho < 12) ? b_mu[ho - 7] : b_ls[ho - 12];
    } else {
#pragma unroll
      for (int q = 0; q < 32; ++q) { h2 t; t.x = (f16)0.f; t.y = (f16)0.f; wp2[q] = t; }
    }
    predreg = (t0 == 0) ? 0.f : dec_pred[b];
    if (lane == 0) pred_s = predreg;
  }
  __syncthreads();

  const float* xrow = x + (long)b * Tn;
  const float* erow = eps + (long)b * Tn;
  const u16* gibase = gi2 + (long)b * G3 * Tc;
  u16* hxrow = hx + ((long)b * Hn + (j < Hn ? j : 0)) * Tc;
  float* outlp = out + (long)b * Tn + t0;
  float* outpr = out + (long)Bn * Tn + (long)b * Tn + t0;
  const int lane3 = j - 192;
  float ep = 0.f;
  float lp0 = 0, lp1 = 0, lp2 = 0, lp3 = 0, lp4 = 0, lp5 = 0, lp6 = 0, lp7 = 0;
  float pr0 = 0, pr1 = 0, pr2 = 0, pr3 = 0, pr4 = 0, pr5 = 0, pr6 = 0, pr7 = 0;

  // heads + coupling on wave 3 for h in Xc; result valid on lane3 0.
  auto couple = [&](float e, const f16* Xc) -> float2 {
    const int hs = lane3 & 1;
    float p = 0.f;
    if (lane3 < 34) {
      const uint4* hp4 = (const uint4*)Xc;
#pragma unroll
      for (int q = 0; q < 8; ++q) {
        uint4 hv = hp4[hs * 8 + q];
        p = fdot2f(bch2(hv.x), wp2[4 * q + 0], p);
        p = fdot2f(bch2(hv.y), wp2[4 * q + 1], p);
        p = fdot2f(bch2(hv.z), wp2[4 * q + 2], p);
        p = fdot2f(bch2(hv.w), wp2[4 * q + 3], p);
      }
    }
    p += __shfl_xor(p, 1);
    float pb = p + hbias;
    const int lj2 = lane3 & 7;
    float pi_ = __shfl(pb, 4 + 2 * lj2);
    float mu_ = __shfl(pb, 14 + 2 * lj2);
    float ls_ = __shfl(pb, 24 + 2 * lj2);
    float shiftv = __shfl(pb, 0);
    float lscv = __shfl(pb, 2);
    const bool valid = (lane3 < 5);
    float wexp = valid ? __expf(pi_) : 0.f;
    float zz = (e - mu_) * __expf(-ls_);
    float uq = __expf(-fabsf(zz));
    float dq = 1.f / (1.f + uq);
    float sigp = (zz >= 0.f) ? dq : uq * dq;
    float sigq = (zz >= 0.f) ? uq * dq : dq;
    float pdfl = uq * dq * dq * __expf(-ls_);
    float c = wexp * sigp, m = wexp * sigq, pq = wexp * pdfl, S = wexp;
    c += __shfl_xor(c, 1, 8); m += __shfl_xor(m, 1, 8);
    pq += __shfl_xor(pq, 1, 8); S += __shfl_xor(S, 1, 8);
    c += __shfl_xor(c, 2, 8); m += __shfl_xor(m, 2, 8);
    pq += __shfl_xor(pq, 2, 8); S += __shfl_xor(S, 2, 8);
    c += __shfl_xor(c, 4, 8); m += __shfl_xor(m, 4, 8);
    pq += __shfl_xor(pq, 4, 8); S += __shfl_xor(S, 4, 8);
    float logc = __logf(c), logm = __logf(m);
    float val = logc - logm;
    float ljac = __logf(pq) + __logf(S) - logc - logm;
    float prednew = fmaf(val, __expf(lscv), shiftv);
    float sp = fmaxf(-e, 0.f) + log1pf(__expf(-fabsf(e)));
    float logp = (-e - 2.f * sp) - lscv - ljac;
    return make_float2(logp, prednew);
  };

  for (int i8 = 0; i8 < Tc; i8 += 8) {
    // -------- per-8-slot batched global I/O --------
    uint4 gR4 = {0, 0, 0, 0}, gZ4 = {0, 0, 0, 0}, gN4 = {0, 0, 0, 0};
    float xc0 = 0, xc1 = 0, xc2 = 0, xc3 = 0, xc4 = 0, xc5 = 0, xc6 = 0, xc7 = 0;
    float ec0 = 0, ec1 = 0, ec2 = 0, ec3 = 0, ec4 = 0, ec5 = 0, ec6 = 0, ec7 = 0;
    u32 hb0 = 0, hb1 = 0, hb2 = 0, hb3 = 0;
    if (j < Hn) {
      if (is_enc) {
        int base = Tn - 8 - t0 - i8; if (base < 0) base = 0;
        float4 v0 = *(const float4*)(xrow + base);
        float4 v1 = *(const float4*)(xrow + base + 4);
        xc0 = v1.w; xc1 = v1.z; xc2 = v1.y; xc3 = v1.x;
        xc4 = v0.w; xc5 = v0.z; xc6 = v0.y; xc7 = v0.x;
      } else {
        gR4 = *(const uint4*)(gibase + (long)j * Tc + i8);
        gZ4 = *(const uint4*)(gibase + (long)(128 + j) * Tc + i8);
        gN4 = *(const uint4*)(gibase + (long)(256 + j) * Tc + i8);
      }
    } else if (j >= 192 && !is_enc) {
      float4 v0 = *(const float4*)(erow + t0 + i8);
      float4 v1 = *(const float4*)(erow + t0 + i8 + 4);
      ec0 = v0.x; ec1 = v0.y; ec2 = v0.z; ec3 = v0.w;
      ec4 = v1.x; ec5 = v1.y; ec6 = v1.z; ec7 = v1.w;
    }
#pragma unroll
    for (int u = 0; u < 8; ++u) {
      const int i = i8 + u;
      float ar = 0, az = 0;
      // ----------------- P1 -----------------
      if (j < Hn) {
        const uint4* hp = (const uint4*)Xp[cur];
        float a0r = 0, a1r = 0, a0z = 0, a1z = 0;
#pragma unroll
        for (int q = 0; q < 16; ++q) {
          uint4 hv = hp[q];
          a0r = fdot2f(bch2(hv.x), wa_[4 * q + 0], a0r);
          a1r = fdot2f(bch2(hv.y), wa_[4 * q + 1], a1r);
          a0r = fdot2f(bch2(hv.z), wa_[4 * q + 2], a0r);
          a1r = fdot2f(bch2(hv.w), wa_[4 * q + 3], a1r);
          a0z = fdot2f(bch2(hv.x), wb_[4 * q + 0], a0z);
          a1z = fdot2f(bch2(hv.y), wb_[4 * q + 1], a1z);
          a0z = fdot2f(bch2(hv.z), wb_[4 * q + 2], a0z);
          a1z = fdot2f(bch2(hv.w), wb_[4 * q + 3], a1z);
        }
        ar = a0r + a1r; az = a0z + a1z;
      } else if (j < 192) {
        const int l = j - 128;
        const uint4* hp = (const uint4*)Xp[cur];
        float a0 = 0, a1 = 0, b0 = 0, b1 = 0;
#pragma unroll
        for (int q = 0; q < 16; ++q) {
          uint4 hv = hp[q];
          a0 = fdot2f(bch2(hv.x), wa_[4 * q + 0], a0);
          a1 = fdot2f(bch2(hv.y), wa_[4 * q + 1], a1);
          a0 = fdot2f(bch2(hv.z), wa_[4 * q + 2], a0);
          a1 = fdot2f(bch2(hv.w), wa_[4 * q + 3], a1);
          b0 = fdot2f(bch2(hv.x), wb_[4 * q + 0], b0);
          b1 = fdot2f(bch2(hv.y), wb_[4 * q + 1], b1);
          b0 = fdot2f(bch2(hv.z), wb_[4 * q + 2], b0);
          b1 = fdot2f(bch2(hv.w), wb_[4 * q + 3], b1);
        }
        float2 nv; nv.x = a0 + a1; nv.y = b0 + b1;
        *(float2*)&nds[2 * l] = nv;
      } else if (!is_enc && i >= 1) {
        float e = (u == 0) ? ep : (u == 1) ? ec0 : (u == 2) ? ec1 : (u == 3) ? ec2
                : (u == 4) ? ec3 : (u == 5) ? ec4 : (u == 6) ? ec5 : ec6;
        float2 rr = couple(e, Xp[cur]);
        if (lane3 == 0) {
          if (u == 0) { lp7 = rr.x; pr7 = rr.y; }
          else if (u == 1) { lp0 = rr.x; pr0 = rr.y; }
          else if (u == 2) { lp1 = rr.x; pr1 = rr.y; }
          else if (u == 3) { lp2 = rr.x; pr2 = rr.y; }
          else if (u == 4) { lp3 = rr.x; pr3 = rr.y; }
          else if (u == 5) { lp4 = rr.x; pr4 = rr.y; }
          else if (u == 6) { lp5 = rr.x; pr5 = rr.y; }
          else { lp6 = rr.x; pr6 = rr.y; }
          pred_s = rr.y;
          predreg = rr.y;
          if (u == 0 && i8 > 0) {
            *(float4*)(outlp + i8 - 8) = make_float4(lp0, lp1, lp2, lp3);
            *(float4*)(outlp + i8 - 4) = make_float4(lp4, lp5, lp6, lp7);
            *(float4*)(outpr + i8 - 8) = make_float4(pr0, pr1, pr2, pr3);
            *(float4*)(outpr + i8 - 4) = make_float4(pr4, pr5, pr6, pr7);
          }
        }
      }
      __syncthreads();                                 // B1: nds + pred_s ready
      // ----------------- P2: gates -----------------
      if (j < Hn) {
        float nd = nds[j];
        float gir, giz, gin;
        if (is_enc) {
          const float xt = (u == 0) ? xc0 : (u == 1) ? xc1 : (u == 2) ? xc2
                          : (u == 3) ? xc3 : (u == 4) ? xc4 : (u == 5) ? xc5
                          : (u == 6) ? xc6 : xc7;
          gir = fmaf(xt, wieR, bieR);
          giz = fmaf(xt, wieZ, bieZ);
          gin = fmaf(xt, wieN, bieN);
        } else {
          u16 gvr = (u == 0) ? (u16)gR4.x : (u == 1) ? (u16)(gR4.x >> 16)
                  : (u == 2) ? (u16)gR4.y : (u == 3) ? (u16)(gR4.y >> 16)
                  : (u == 4) ? (u16)gR4.z : (u == 5) ? (u16)(gR4.z >> 16)
                  : (u == 6) ? (u16)gR4.w : (u16)(gR4.w >> 16);
          u16 gvz = (u == 0) ? (u16)gZ4.x : (u == 1) ? (u16)(gZ4.x >> 16)
                  : (u == 2) ? (u16)gZ4.y : (u == 3) ? (u16)(gZ4.y >> 16)
                  : (u == 4) ? (u16)gZ4.z : (u == 5) ? (u16)(gZ4.z >> 16)
                  : (u == 6) ? (u16)gZ4.w : (u16)(gZ4.w >> 16);
          u16 gvn = (u == 0) ? (u16)gN4.x : (u == 1) ? (u16)(gN4.x >> 16)
                  : (u == 2) ? (u16)gN4.y : (u == 3) ? (u16)(gN4.y >> 16)
                  : (u == 4) ? (u16)gN4.z : (u == 5) ? (u16)(gN4.z >> 16)
                  : (u == 6) ? (u16)gN4.w : (u16)(gN4.w >> 16);
          float pred = pred_s;
          gir = h2f(gvr) + pred * wr0;
          giz = h2f(gvz) + pred * wz0;
          gin = h2f(gvn) + pred * wn0;
        }
        float r = sigm(ar + gir);
        float z = sigm(az + giz);
        float n = tanh_fast(gin + r * (nd + bhn));
        hm = (1.f - z) * n + z * hm;
        Xp[cur ^ 1][j] = (f16)hm;
        if (is_enc) {
          u16 hv16 = f2h(hm);
          if (u == 0) hb0 = hv16; else if (u == 1) hb0 |= ((u32)hv16 << 16);
          else if (u == 2) hb1 = hv16; else if (u == 3) hb1 |= ((u32)hv16 << 16);
          else if (u == 4) hb2 = hv16; else if (u == 5) hb2 |= ((u32)hv16 << 16);
          else if (u == 6) hb3 = hv16; else hb3 |= ((u32)hv16 << 16);
        }
      }
      __syncthreads();                                 // B2: Xp(next) ready
      cur ^= 1;
    }
    if (is_enc && j < Hn) {
      uint4 o; o.x = hb0; o.y = hb1; o.z = hb2; o.w = hb3;
      *(uint4*)(hxrow + i8) = o;
    }
    if (!is_enc && j >= 192) ep = ec7;
  }
  // trailing couple for step Tc-1 + final batch store
  if (!is_enc && j >= 192) {
    float2 rr = couple(ep, Xp[cur]);
    if (lane3 == 0) {
      lp7 = rr.x; pr7 = rr.y; predreg = rr.y;
      *(float4*)(outlp + Tc - 8) = make_float4(lp0, lp1, lp2, lp3);
      *(float4*)(outlp + Tc - 4) = make_float4(lp4, lp5, lp6, lp7);
      *(float4*)(outpr + Tc - 8) = make_float4(pr0, pr1, pr2, pr3);
      *(float4*)(outpr + Tc - 4) = make_float4(pr4, pr5, pr6, pr7);
    }
  }
  if (j < Hn) (is_enc ? enc_h : dec_h)[(long)b * Hn + j] = hm;
  if (!is_enc && j == 192) dec_pred[b] = predreg;
}

// ---- GEMM: gi2[b][col][t] = hx[b][:][t]^T @ Wi_d[1:,:] + bi_d  (fp32 acc) ----
// A2 layout: [b][k][tt] ; C2 layout: [b][col][tt]  (both f16, t contiguous)
__global__ __launch_bounds__(256) void gemm_gi(
    const u16* __restrict__ A2, const float* __restrict__ Wi_d,
    const float* __restrict__ bi_d, u16* __restrict__ C2, int Tc)
{
  __shared__ __align__(16) float As[16][64];  // [k][m]
  __shared__ __align__(16) float Ws[16][64];  // [k][n]
  const int tid = threadIdx.x;
  const long m0 = (long)blockIdx.x * 64;      // m = b*Tc + tt
  const int n0 = blockIdx.y * 64;
  const int bb = (int)(m0 / Tc);
  const int tt0 = (int)(m0 - (long)bb * Tc);
  const int tx = tid & 15, ty = tid >> 4;
  const int lk = tid >> 4, lm = (tid & 15) * 4;   // A-load: k row, 4 tt's
  const int wk = tid >> 4, wn = (tid & 15) * 4;
  float acc[4][4] = {};
  for (int k0 = 0; k0 < Hn; k0 += 16) {
    uint2 a2v = *(const uint2*)(A2 + ((long)bb * Hn + k0 + lk) * Tc + tt0 + lm);
    float4 w4 = *(const float4*)(Wi_d + (long)(1 + k0 + wk) * G3 + n0 + wn);
    __syncthreads();
    As[lk][lm + 0] = h2f((u16)(a2v.x & 0xffffu));
    As[lk][lm + 1] = h2f((u16)(a2v.x >> 16));
    As[lk][lm + 2] = h2f((u16)(a2v.y & 0xffffu));
    As[lk][lm + 3] = h2f((u16)(a2v.y >> 16));
    *(float4*)&Ws[wk][wn] = w4;
    __syncthreads();
#pragma unroll
    for (int kk = 0; kk < 16; ++kk) {
      float4 av = *(const float4*)&As[kk][ty * 4];
      float4 wv = *(const float4*)&Ws[kk][tx * 4];
      float ar[4] = {av.x, av.y, av.z, av.w};
      float wr[4] = {wv.x, wv.y, wv.z, wv.w};
#pragma unroll
      for (int i = 0; i < 4; ++i)
#pragma unroll
        for (int jj = 0; jj < 4; ++jj) acc[i][jj] = fmaf(ar[i], wr[jj], acc[i][jj]);
    }
  }
  const float4 bbv = *(const float4*)(bi_d + n0 + tx * 4);
  const float br[4] = {bbv.x, bbv.y, bbv.z, bbv.w};
#pragma unroll
  for (int jj = 0; jj < 4; ++jj) {
    int colc = n0 + tx * 4 + jj;
    u32 lo = (u32)f2h(acc[0][jj] + br[jj]) | ((u32)f2h(acc[1][jj] + br[jj]) << 16);
    u32 hi = (u32)f2h(acc[2][jj] + br[jj]) | ((u32)f2h(acc[3][jj] + br[jj]) << 16);
    uint2 o; o.x = lo; o.y = hi;
    *(uint2*)(C2 + ((long)bb * G3 + colc) * Tc + tt0 + ty * 4) = o;
  }
}

extern "C" void kernel_launch(void* const* d_in, const int* in_sizes, int n_in,
                              void* d_out, int out_size, void* d_ws, size_t ws_size,
                              hipStream_t stream) {
  const float* x = (const float*)d_in[1];
  const float* eps = (const float*)d_in[2];
  const float* Wi_e = (const float*)d_in[3];
  const float* Wh_e = (const float*)d_in[4];
  const float* bi_e = (const float*)d_in[5];
  const float* bhn_e = (const float*)d_in[6];
  const float* Wi_d = (const float*)d_in[7];
  const float* Wh_d = (const float*)d_in[8];
  const float* bi_d = (const float*)d_in[9];
  const float* bhn_d = (const float*)d_in[10];
  const float* W_shift = (const float*)d_in[11];
  const float* b_shift = (const float*)d_in[12];
  const float* W_lsc = (const float*)d_in[13];
  const float* b_lsc = (const float*)d_in[14];
  const float* W_pi = (const float*)d_in[15];
  const float* b_pi = (const float*)d_in[16];
  const float* W_mu = (const float*)d_in[17];
  const float* b_mu = (const float*)d_in[18];
  const float* W_ls = (const float*)d_in[19];
  const float* b_ls = (const float*)d_in[20];
  float* out = (float*)d_out;

  const size_t stateB = (size_t)(2 * Bn * Hn + Bn) * sizeof(float);
  const size_t stateAl = (stateB + 255) & ~(size_t)255;
  int Tc = 512;  // 8 chunks: enc(k) || dec(k-1) pipeline
  while (Tc > 64 && stateAl + (size_t)Bn * Tc * (Hn + G3) * 2 > ws_size) Tc >>= 1;
  if (stateAl + (size_t)Bn * Tc * (Hn + G3) * 2 > ws_size) return;

  float* enc_h = (float*)d_ws;
  float* dec_h = enc_h + (size_t)Bn * Hn;
  float* dec_pred = dec_h + (size_t)Bn * Hn;
  u16* hx = (u16*)((char*)d_ws + stateAl);          // [b][k][t]
  u16* gi = hx + (size_t)Bn * Tc * Hn;              // [b][col][t]

  const int Nc = Tn / Tc;
  const dim3 gg((unsigned)(((size_t)Bn * Tc) / 64), G3 / 64);
  for (int k = 0; k <= Nc; ++k) {
    int enc_t0 = (k < Nc) ? k * Tc : -1;
    int dec_t0 = (k >= 1) ? (k - 1) * Tc : -1;
    combo_kernel<<<2 * Bn, NTH, 0, stream>>>(
        x, Wi_e, Wh_e, bi_e, bhn_e, hx, enc_h,
        eps, Wi_d, Wh_d, bhn_d, W_shift, b_shift, W_lsc, b_lsc,
        W_pi, b_pi, W_mu, b_mu, W_ls, b_ls,
        gi, out, dec_h, dec_pred, enc_t0, dec_t0, Tc);
    if (k < Nc) gemm_gi<<<gg, 256, 0, stream>>>(hx, Wi_d, bi_d, gi, Tc);
  }
}